// Round 1
// baseline (495.905 us; speedup 1.0000x reference)
//
#include <hip/hip_runtime.h>

#define S_LEN 4096
#define DMODEL 1024
#define NHEADS 16
#define DKH 64
#define WIN 256
#define GTOK 64

typedef unsigned short u16t;
typedef __attribute__((ext_vector_type(8))) short short8;
typedef __attribute__((ext_vector_type(4))) float f32x4;

__device__ __forceinline__ u16t f2bf(float x) {
  union { float f; unsigned int u; } v; v.f = x;
  unsigned int r = v.u + 0x7FFFu + ((v.u >> 16) & 1u);
  return (u16t)(r >> 16);
}

// ---------------- fp32 -> bf16 convert ----------------
__global__ void cvt_kernel(const float* __restrict__ src, u16t* __restrict__ dst, int n) {
  int i = (blockIdx.x * blockDim.x + threadIdx.x) * 4;
  if (i >= n) return;
  float4 f = *(const float4*)(src + i);
  unsigned int lo = (unsigned int)f2bf(f.x) | ((unsigned int)f2bf(f.y) << 16);
  unsigned int hi = (unsigned int)f2bf(f.z) | ((unsigned int)f2bf(f.w) << 16);
  *(uint2*)(dst + i) = make_uint2(lo, hi);
}

// ---------------- bf16 GEMM: Y = A(M,K) @ B(N,K)^T + bias, * alpha ----------------
#define BM 128
#define BN 128
#define BK 32
#define LDT 40   // LDS row stride in u16 (80B = 5*16B: aligned b128, ~2-way banks)

template<int OUT_F32>
__global__ __launch_bounds__(256)
void gemm_bt(const u16t* __restrict__ A, const u16t* __restrict__ B,
             const float* __restrict__ bias, void* __restrict__ Y,
             int M, int N, int K, float alpha)
{
  __shared__ __align__(16) u16t sA[BM * LDT];
  __shared__ __align__(16) u16t sB[BN * LDT];

  const int tid = threadIdx.x;
  const int lane = tid & 63;
  const int lr = lane & 15, lg = lane >> 4;
  const int w = tid >> 6;
  const int wm = (w >> 1) * 64, wn = (w & 1) * 64;
  const int m0 = blockIdx.y * BM, n0 = blockIdx.x * BN;

  f32x4 acc[4][4] = {};
  uint4 ra[2], rb[2];

  const int nk = K / BK;

  // prologue: tile 0 global->reg->lds
#pragma unroll
  for (int j = 0; j < 2; ++j) {
    int c = tid + j * 256, row = c >> 2, kb = c & 3;
    ra[j] = *(const uint4*)(A + (size_t)(m0 + row) * K + kb * 8);
    rb[j] = *(const uint4*)(B + (size_t)(n0 + row) * K + kb * 8);
  }
#pragma unroll
  for (int j = 0; j < 2; ++j) {
    int c = tid + j * 256, row = c >> 2, kb = c & 3;
    *(uint4*)&sA[row * LDT + kb * 8] = ra[j];
    *(uint4*)&sB[row * LDT + kb * 8] = rb[j];
  }
  __syncthreads();

  for (int kt = 0; kt < nk; ++kt) {
    if (kt + 1 < nk) {  // issue next tile's global loads early (hide under MFMA)
#pragma unroll
      for (int j = 0; j < 2; ++j) {
        int c = tid + j * 256, row = c >> 2, kb = c & 3;
        ra[j] = *(const uint4*)(A + (size_t)(m0 + row) * K + (kt + 1) * BK + kb * 8);
        rb[j] = *(const uint4*)(B + (size_t)(n0 + row) * K + (kt + 1) * BK + kb * 8);
      }
    }
    short8 af[4], bf[4];
#pragma unroll
    for (int mf = 0; mf < 4; ++mf)
      af[mf] = *(const short8*)&sA[(wm + mf * 16 + lr) * LDT + lg * 8];
#pragma unroll
    for (int nf = 0; nf < 4; ++nf)
      bf[nf] = *(const short8*)&sB[(wn + nf * 16 + lr) * LDT + lg * 8];
#pragma unroll
    for (int mf = 0; mf < 4; ++mf)
#pragma unroll
      for (int nf = 0; nf < 4; ++nf)
        acc[mf][nf] = __builtin_amdgcn_mfma_f32_16x16x32_bf16(af[mf], bf[nf], acc[mf][nf], 0, 0, 0);

    if (kt + 1 < nk) {
      __syncthreads();   // all waves done reading current tile
#pragma unroll
      for (int j = 0; j < 2; ++j) {
        int c = tid + j * 256, row = c >> 2, kb = c & 3;
        *(uint4*)&sA[row * LDT + kb * 8] = ra[j];
        *(uint4*)&sB[row * LDT + kb * 8] = rb[j];
      }
      __syncthreads();   // next tile staged
    }
  }

  // epilogue: bias, alpha, store
#pragma unroll
  for (int nf = 0; nf < 4; ++nf) {
    int col = n0 + wn + nf * 16 + lr;
    float bv = bias[col];
#pragma unroll
    for (int mf = 0; mf < 4; ++mf)
#pragma unroll
      for (int r = 0; r < 4; ++r) {
        int row = m0 + wm + mf * 16 + lg * 4 + r;
        float v = (acc[mf][nf][r] + bv) * alpha;
        if (OUT_F32) ((float*)Y)[(size_t)row * N + col] = v;
        else         ((u16t*)Y)[(size_t)row * N + col] = f2bf(v);
      }
  }
}

// ---------------- flash-style sparse attention ----------------
#define KLDT 72  // 144B row stride (9*16B)

__global__ __launch_bounds__(256)
void attn_kernel(const u16t* __restrict__ Qp, const u16t* __restrict__ Kp,
                 const u16t* __restrict__ Vp, u16t* __restrict__ AO)
{
  __shared__ __align__(16) u16t sK[64 * KLDT];
  __shared__ __align__(16) u16t sVt[64 * KLDT];
  __shared__ __align__(16) u16t sP[4][16 * KLDT];

  const int qb = blockIdx.x, h = blockIdx.y;
  const int tid = threadIdx.x, w = tid >> 6, lane = tid & 63;
  const int lr = lane & 15, lg = lane >> 4;
  const int qw = qb * 64 + w * 16;  // this wave's first q row

  // Q fragments resident in registers (Q pre-scaled by 1/sqrt(dk))
  short8 qf[2];
#pragma unroll
  for (int kk = 0; kk < 2; ++kk)
    qf[kk] = *(const short8*)(Qp + (size_t)(qw + lr) * DMODEL + h * DKH + kk * 32 + lg * 8);

  f32x4 acc[4] = {};
  float m_run[4], l_run[4];
#pragma unroll
  for (int r = 0; r < 4; ++r) { m_run[r] = -1e30f; l_run[r] = 0.f; }

  const int lo = (qb - 4 < 1) ? 1 : qb - 4;
  const int hi = (qb + 4 > 63) ? 63 : qb + 4;
  const int nkv = (qb == 0) ? 64 : (hi - lo + 2);

  for (int idx = 0; idx < nkv; ++idx) {
    const int kvb = (qb == 0) ? idx : ((idx == 0) ? 0 : lo + idx - 1);
    const int kv0 = kvb * 64;

    __syncthreads();  // previous tile fully consumed
    // stage K (row-major) and V (transposed, XOR-swizzled) into LDS
#pragma unroll
    for (int j = 0; j < 2; ++j) {
      int c = tid + j * 256, row = c >> 3, col8 = c & 7;
      const u16t* gk = Kp + (size_t)(kv0 + row) * DMODEL + h * DKH + col8 * 8;
      const u16t* gv = Vp + (size_t)(kv0 + row) * DMODEL + h * DKH + col8 * 8;
      uint4 kvv = *(const uint4*)gk;
      *(uint4*)&sK[row * KLDT + col8 * 8] = kvv;
      union { uint4 u4; u16t s[8]; } uv; uv.u4 = *(const uint4*)gv;
#pragma unroll
      for (int e = 0; e < 8; ++e) {
        int d = col8 * 8 + e;
        sVt[d * KLDT + (row ^ ((d >> 3) << 3))] = uv.s[e];
      }
    }
    __syncthreads();

    // S = Q K^T (Q already scaled)
    f32x4 sacc[4] = {};
#pragma unroll
    for (int kk = 0; kk < 2; ++kk)
#pragma unroll
      for (int nf = 0; nf < 4; ++nf) {
        short8 kf = *(const short8*)&sK[(nf * 16 + lr) * KLDT + kk * 32 + lg * 8];
        sacc[nf] = __builtin_amdgcn_mfma_f32_16x16x32_bf16(qf[kk], kf, sacc[nf], 0, 0, 0);
      }

    // mask + online softmax (rows = lg*4+r, cols = nf*16+lr)
    float p[4][4];
#pragma unroll
    for (int r = 0; r < 4; ++r) {
      int qg = qw + lg * 4 + r;
      float rm = -1e30f;
#pragma unroll
      for (int nf = 0; nf < 4; ++nf) {
        int sg = kv0 + nf * 16 + lr;
        int diff = qg - sg; if (diff < 0) diff = -diff;
        bool ok = (qg < GTOK) || (sg < GTOK) || (diff <= WIN);
        float x = ok ? sacc[nf][r] : -1e30f;
        p[nf][r] = x;
        rm = fmaxf(rm, x);
      }
#pragma unroll
      for (int off = 1; off < 16; off <<= 1) rm = fmaxf(rm, __shfl_xor(rm, off, 16));
      float mnew = fmaxf(m_run[r], rm);
      float corr = __expf(m_run[r] - mnew);
      m_run[r] = mnew;
      float rs = 0.f;
#pragma unroll
      for (int nf = 0; nf < 4; ++nf) {
        float e = __expf(p[nf][r] - mnew);
        p[nf][r] = e;
        rs += e;
      }
#pragma unroll
      for (int off = 1; off < 16; off <<= 1) rs += __shfl_xor(rs, off, 16);
      l_run[r] = l_run[r] * corr + rs;
#pragma unroll
      for (int nf = 0; nf < 4; ++nf) acc[nf][r] *= corr;
    }

    // P -> LDS (bf16), wave-private region
#pragma unroll
    for (int nf = 0; nf < 4; ++nf)
#pragma unroll
      for (int r = 0; r < 4; ++r)
        sP[w][(lg * 4 + r) * KLDT + nf * 16 + lr] = f2bf(p[nf][r]);

    // O += P V
#pragma unroll
    for (int kk = 0; kk < 2; ++kk) {
      short8 pf = *(const short8*)&sP[w][lr * KLDT + kk * 32 + lg * 8];
#pragma unroll
      for (int nf = 0; nf < 4; ++nf) {
        int d = nf * 16 + lr;
        int s0 = kk * 32 + lg * 8;
        short8 vf = *(const short8*)&sVt[d * KLDT + (s0 ^ ((d >> 3) << 3))];
        acc[nf] = __builtin_amdgcn_mfma_f32_16x16x32_bf16(pf, vf, acc[nf], 0, 0, 0);
      }
    }
  }

  // epilogue: normalize, store bf16 to (S, D_MODEL)
#pragma unroll
  for (int nf = 0; nf < 4; ++nf)
#pragma unroll
    for (int r = 0; r < 4; ++r) {
      float v = acc[nf][r] / l_run[r];
      AO[(size_t)(qw + lg * 4 + r) * DMODEL + h * DKH + nf * 16 + lr] = f2bf(v);
    }
}

// ---------------- launch ----------------
extern "C" void kernel_launch(void* const* d_in, const int* in_sizes, int n_in,
                              void* d_out, int out_size, void* d_ws, size_t ws_size,
                              hipStream_t stream) {
  const float* q   = (const float*)d_in[0];
  const float* k   = (const float*)d_in[1];
  const float* v   = (const float*)d_in[2];
  const float* w_q = (const float*)d_in[3];
  const float* b_q = (const float*)d_in[4];
  const float* w_k = (const float*)d_in[5];
  const float* b_k = (const float*)d_in[6];
  const float* w_v = (const float*)d_in[7];
  const float* b_v = (const float*)d_in[8];
  const float* w_o = (const float*)d_in[9];
  const float* b_o = (const float*)d_in[10];

  u16t* ws = (u16t*)d_ws;
  const size_t SZX = (size_t)S_LEN * DMODEL;   // 4,194,304
  const size_t SZW = (size_t)DMODEL * DMODEL;  // 1,048,576
  u16t* xb  = ws;
  u16t* wb0 = ws + SZX;
  u16t* wb1 = wb0 + SZW;
  u16t* wb2 = wb1 + SZW;
  u16t* wb3 = wb2 + SZW;
  u16t* Qp  = wb3 + SZW;
  u16t* Kp  = Qp + SZX;
  u16t* Vp  = Kp + SZX;
  u16t* AO  = Vp + SZX;

  dim3 blk(256);
  dim3 ggrid(DMODEL / BN, S_LEN / BM);
  const float scale = 0.125f;  // 1/sqrt(64)

  cvt_kernel<<<(int)(SZW / 1024), blk, 0, stream>>>(w_q, wb0, (int)SZW);
  cvt_kernel<<<(int)(SZW / 1024), blk, 0, stream>>>(w_k, wb1, (int)SZW);
  cvt_kernel<<<(int)(SZW / 1024), blk, 0, stream>>>(w_v, wb2, (int)SZW);
  cvt_kernel<<<(int)(SZW / 1024), blk, 0, stream>>>(w_o, wb3, (int)SZW);

  cvt_kernel<<<(int)(SZX / 1024), blk, 0, stream>>>(q, xb, (int)SZX);
  gemm_bt<0><<<ggrid, blk, 0, stream>>>(xb, wb0, b_q, Qp, S_LEN, DMODEL, DMODEL, scale);
  cvt_kernel<<<(int)(SZX / 1024), blk, 0, stream>>>(k, xb, (int)SZX);
  gemm_bt<0><<<ggrid, blk, 0, stream>>>(xb, wb1, b_k, Kp, S_LEN, DMODEL, DMODEL, 1.0f);
  cvt_kernel<<<(int)(SZX / 1024), blk, 0, stream>>>(v, xb, (int)SZX);
  gemm_bt<0><<<ggrid, blk, 0, stream>>>(xb, wb2, b_v, Vp, S_LEN, DMODEL, DMODEL, 1.0f);

  attn_kernel<<<dim3(S_LEN / 64, NHEADS), blk, 0, stream>>>(Qp, Kp, Vp, AO);

  gemm_bt<1><<<ggrid, blk, 0, stream>>>(AO, wb3, b_o, d_out, S_LEN, DMODEL, DMODEL, 1.0f);
}

// Round 3
// 291.406 us; speedup vs baseline: 1.7018x; 1.7018x over previous
//
#include <hip/hip_runtime.h>

#define S_LEN 4096
#define DMODEL 1024
#define NHEADS 16
#define DKH 64
#define WIN 256
#define GTOK 64
#define NSPLIT 8

typedef unsigned short u16t;
typedef __attribute__((ext_vector_type(8))) short short8;
typedef __attribute__((ext_vector_type(4))) float f32x4;

__device__ __forceinline__ u16t f2bf(float x) {
  union { float f; unsigned int u; } v; v.f = x;
  unsigned int r = v.u + 0x7FFFu + ((v.u >> 16) & 1u);
  return (u16t)(r >> 16);
}

// ---------------- fp32 -> bf16 convert ----------------
__global__ void cvt_kernel(const float* __restrict__ src, u16t* __restrict__ dst, int n) {
  int i = (blockIdx.x * blockDim.x + threadIdx.x) * 4;
  if (i >= n) return;
  float4 f = *(const float4*)(src + i);
  unsigned int lo = (unsigned int)f2bf(f.x) | ((unsigned int)f2bf(f.y) << 16);
  unsigned int hi = (unsigned int)f2bf(f.z) | ((unsigned int)f2bf(f.w) << 16);
  *(uint2*)(dst + i) = make_uint2(lo, hi);
}

// ---------------- bf16 GEMM: Y = A(M,K) @ B(N,K)^T + bias, * alpha ----------------
#define BM 128
#define BN 128
#define BK 32
#define LDT 40

template<int OUT_F32>
__global__ __launch_bounds__(256)
void gemm_bt(const u16t* __restrict__ A, const u16t* __restrict__ B,
             const float* __restrict__ bias, void* __restrict__ Y,
             int M, int N, int K, float alpha)
{
  __shared__ __align__(16) u16t sA[BM * LDT];
  __shared__ __align__(16) u16t sB[BN * LDT];

  const int tid = threadIdx.x;
  const int lane = tid & 63;
  const int lr = lane & 15, lg = lane >> 4;
  const int w = tid >> 6;
  const int wm = (w >> 1) * 64, wn = (w & 1) * 64;
  const int m0 = blockIdx.y * BM, n0 = blockIdx.x * BN;

  f32x4 acc[4][4] = {};
  uint4 ra[2], rb[2];

  const int nk = K / BK;

#pragma unroll
  for (int j = 0; j < 2; ++j) {
    int c = tid + j * 256, row = c >> 2, kb = c & 3;
    ra[j] = *(const uint4*)(A + (size_t)(m0 + row) * K + kb * 8);
    rb[j] = *(const uint4*)(B + (size_t)(n0 + row) * K + kb * 8);
  }
#pragma unroll
  for (int j = 0; j < 2; ++j) {
    int c = tid + j * 256, row = c >> 2, kb = c & 3;
    *(uint4*)&sA[row * LDT + kb * 8] = ra[j];
    *(uint4*)&sB[row * LDT + kb * 8] = rb[j];
  }
  __syncthreads();

  for (int kt = 0; kt < nk; ++kt) {
    if (kt + 1 < nk) {
#pragma unroll
      for (int j = 0; j < 2; ++j) {
        int c = tid + j * 256, row = c >> 2, kb = c & 3;
        ra[j] = *(const uint4*)(A + (size_t)(m0 + row) * K + (kt + 1) * BK + kb * 8);
        rb[j] = *(const uint4*)(B + (size_t)(n0 + row) * K + (kt + 1) * BK + kb * 8);
      }
    }
    short8 af[4], bf[4];
#pragma unroll
    for (int mf = 0; mf < 4; ++mf)
      af[mf] = *(const short8*)&sA[(wm + mf * 16 + lr) * LDT + lg * 8];
#pragma unroll
    for (int nf = 0; nf < 4; ++nf)
      bf[nf] = *(const short8*)&sB[(wn + nf * 16 + lr) * LDT + lg * 8];
#pragma unroll
    for (int mf = 0; mf < 4; ++mf)
#pragma unroll
      for (int nf = 0; nf < 4; ++nf)
        acc[mf][nf] = __builtin_amdgcn_mfma_f32_16x16x32_bf16(af[mf], bf[nf], acc[mf][nf], 0, 0, 0);

    if (kt + 1 < nk) {
      __syncthreads();
#pragma unroll
      for (int j = 0; j < 2; ++j) {
        int c = tid + j * 256, row = c >> 2, kb = c & 3;
        *(uint4*)&sA[row * LDT + kb * 8] = ra[j];
        *(uint4*)&sB[row * LDT + kb * 8] = rb[j];
      }
      __syncthreads();
    }
  }

#pragma unroll
  for (int nf = 0; nf < 4; ++nf) {
    int col = n0 + wn + nf * 16 + lr;
    float bv = bias[col];
#pragma unroll
    for (int mf = 0; mf < 4; ++mf)
#pragma unroll
      for (int r = 0; r < 4; ++r) {
        int row = m0 + wm + mf * 16 + lg * 4 + r;
        float v = (acc[mf][nf][r] + bv) * alpha;
        if (OUT_F32) ((float*)Y)[(size_t)row * N + col] = v;
        else         ((u16t*)Y)[(size_t)row * N + col] = f2bf(v);
      }
  }
}

// ---------------- flash-style sparse attention ----------------
#define KLDT 72  // LDS row stride in u16 (144B)

// grid.x: 0..62 -> windowed blocks qb=1..63; 63..63+NSPLIT-1 -> global-q KV splits
__global__ __launch_bounds__(256)
void attn_kernel(const u16t* __restrict__ Qp, const u16t* __restrict__ Kp,
                 const u16t* __restrict__ Vp, u16t* __restrict__ AO,
                 float* __restrict__ pacc, float* __restrict__ pml)
{
  __shared__ __align__(16) u16t sK[64 * KLDT];
  __shared__ __align__(16) u16t sVt[64 * KLDT];
  __shared__ __align__(16) u16t sP[4][16 * KLDT];

  const int h = blockIdx.y;
  const int tid = threadIdx.x, w = tid >> 6, lane = tid & 63;
  const int lr = lane & 15, lg = lane >> 4;

  const bool windowed = (blockIdx.x < 63);
  const int qb = windowed ? (blockIdx.x + 1) : 0;
  const int split = windowed ? 0 : (blockIdx.x - 63);
  const int qw = qb * 64 + w * 16;

  // Q fragments (Q pre-scaled by 1/sqrt(dk))
  short8 qf[2];
#pragma unroll
  for (int kk = 0; kk < 2; ++kk)
    qf[kk] = *(const short8*)(Qp + (size_t)(qw + lr) * DMODEL + h * DKH + kk * 32 + lg * 8);

  f32x4 acc[4] = {};
  float m_run[4], l_run[4];
#pragma unroll
  for (int r = 0; r < 4; ++r) { m_run[r] = -1e30f; l_run[r] = 0.f; }

  int lo = 1, nkv;
  if (windowed) {
    lo = (qb - 4 < 1) ? 1 : qb - 4;
    int hi = (qb + 4 > 63) ? 63 : qb + 4;
    nkv = hi - lo + 2;  // {0} ∪ [lo..hi]
  } else {
    nkv = 64 / NSPLIT;  // 8 KV blocks per split
  }

  uint4 rk[2], rv[2];

  // kvb for iteration idx
#define KVB(idx) (windowed ? ((idx) == 0 ? 0 : lo + (idx) - 1) : (split * (64 / NSPLIT) + (idx)))

  // prologue: load + stage tile 0
  {
    int kv0 = KVB(0) * 64;
#pragma unroll
    for (int j = 0; j < 2; ++j) {
      int c = tid + j * 256, row = c >> 3, col8 = c & 7;
      rk[j] = *(const uint4*)(Kp + (size_t)(kv0 + row) * DMODEL + h * DKH + col8 * 8);
      rv[j] = *(const uint4*)(Vp + (size_t)(kv0 + row) * DMODEL + h * DKH + col8 * 8);
    }
#pragma unroll
    for (int j = 0; j < 2; ++j) {
      int c = tid + j * 256, row = c >> 3, col8 = c & 7;
      *(uint4*)&sK[row * KLDT + col8 * 8] = rk[j];
      union { uint4 u4; u16t s[8]; } uv; uv.u4 = rv[j];
#pragma unroll
      for (int e = 0; e < 8; ++e) {
        int d = col8 * 8 + e;
        sVt[d * KLDT + (row ^ ((d >> 3) << 3))] = uv.s[e];
      }
    }
  }
  __syncthreads();

  for (int idx = 0; idx < nkv; ++idx) {
    const int kv0 = KVB(idx) * 64;

    // issue next tile's global loads early (hide latency under compute)
    if (idx + 1 < nkv) {
      int nkv0 = KVB(idx + 1) * 64;
#pragma unroll
      for (int j = 0; j < 2; ++j) {
        int c = tid + j * 256, row = c >> 3, col8 = c & 7;
        rk[j] = *(const uint4*)(Kp + (size_t)(nkv0 + row) * DMODEL + h * DKH + col8 * 8);
        rv[j] = *(const uint4*)(Vp + (size_t)(nkv0 + row) * DMODEL + h * DKH + col8 * 8);
      }
    }

    // S = Q K^T
    f32x4 sacc[4] = {};
#pragma unroll
    for (int kk = 0; kk < 2; ++kk)
#pragma unroll
      for (int nf = 0; nf < 4; ++nf) {
        short8 kf = *(const short8*)&sK[(nf * 16 + lr) * KLDT + kk * 32 + lg * 8];
        sacc[nf] = __builtin_amdgcn_mfma_f32_16x16x32_bf16(qf[kk], kf, sacc[nf], 0, 0, 0);
      }

    // mask (only windowed tiles with kv0>0 need it: sg>=64 there, qg>=64 always)
    if (windowed && kv0 > 0) {
#pragma unroll
      for (int r = 0; r < 4; ++r) {
        int qg = qw + lg * 4 + r;
#pragma unroll
        for (int nf = 0; nf < 4; ++nf) {
          int sg = kv0 + nf * 16 + lr;
          int diff = qg - sg; if (diff < 0) diff = -diff;
          if (diff > WIN) sacc[nf][r] = -1e30f;
        }
      }
    }

    // online softmax (rows = lg*4+r, cols = nf*16+lr)
    float p[4][4];
#pragma unroll
    for (int r = 0; r < 4; ++r) {
      float rm = -1e30f;
#pragma unroll
      for (int nf = 0; nf < 4; ++nf) { p[nf][r] = sacc[nf][r]; rm = fmaxf(rm, p[nf][r]); }
#pragma unroll
      for (int off = 1; off < 16; off <<= 1) rm = fmaxf(rm, __shfl_xor(rm, off, 16));
      float mnew = fmaxf(m_run[r], rm);
      float corr = __expf(m_run[r] - mnew);
      m_run[r] = mnew;
      float rs = 0.f;
#pragma unroll
      for (int nf = 0; nf < 4; ++nf) {
        float e = __expf(p[nf][r] - mnew);
        p[nf][r] = e;
        rs += e;
      }
#pragma unroll
      for (int off = 1; off < 16; off <<= 1) rs += __shfl_xor(rs, off, 16);
      l_run[r] = l_run[r] * corr + rs;
#pragma unroll
      for (int nf = 0; nf < 4; ++nf) acc[nf][r] *= corr;
    }

    // P -> LDS (wave-private region)
#pragma unroll
    for (int nf = 0; nf < 4; ++nf)
#pragma unroll
      for (int r = 0; r < 4; ++r)
        sP[w][(lg * 4 + r) * KLDT + nf * 16 + lr] = f2bf(p[nf][r]);

    // O += P V
#pragma unroll
    for (int kk = 0; kk < 2; ++kk) {
      short8 pf = *(const short8*)&sP[w][lr * KLDT + kk * 32 + lg * 8];
#pragma unroll
      for (int nf = 0; nf < 4; ++nf) {
        int d = nf * 16 + lr;
        int s0 = kk * 32 + lg * 8;
        short8 vf = *(const short8*)&sVt[d * KLDT + (s0 ^ ((d >> 3) << 3))];
        acc[nf] = __builtin_amdgcn_mfma_f32_16x16x32_bf16(pf, vf, acc[nf], 0, 0, 0);
      }
    }

    // stage next tile
    if (idx + 1 < nkv) {
      __syncthreads();
#pragma unroll
      for (int j = 0; j < 2; ++j) {
        int c = tid + j * 256, row = c >> 3, col8 = c & 7;
        *(uint4*)&sK[row * KLDT + col8 * 8] = rk[j];
        union { uint4 u4; u16t s[8]; } uv; uv.u4 = rv[j];
#pragma unroll
        for (int e = 0; e < 8; ++e) {
          int d = col8 * 8 + e;
          sVt[d * KLDT + (row ^ ((d >> 3) << 3))] = uv.s[e];
        }
      }
      __syncthreads();
    }
  }
#undef KVB

  if (windowed) {
#pragma unroll
    for (int nf = 0; nf < 4; ++nf)
#pragma unroll
      for (int r = 0; r < 4; ++r) {
        float v = acc[nf][r] / l_run[r];
        AO[(size_t)(qw + lg * 4 + r) * DMODEL + h * DKH + nf * 16 + lr] = f2bf(v);
      }
  } else {
    // write partial (m, l, acc) for merge
    const int pbase = (h * NSPLIT + split) * 64;
#pragma unroll
    for (int nf = 0; nf < 4; ++nf)
#pragma unroll
      for (int r = 0; r < 4; ++r)
        pacc[(size_t)(pbase + w * 16 + lg * 4 + r) * 64 + nf * 16 + lr] = acc[nf][r];
    if (lr == 0) {
#pragma unroll
      for (int r = 0; r < 4; ++r) {
        int b = (pbase + w * 16 + lg * 4 + r) * 2;
        pml[b] = m_run[r];
        pml[b + 1] = l_run[r];
      }
    }
  }
}

// ---------------- merge partials for global q rows ----------------
__global__ __launch_bounds__(256)
void merge_kernel(const float* __restrict__ pacc, const float* __restrict__ pml,
                  u16t* __restrict__ AO)
{
  const int h = blockIdx.x;
  const int tid = threadIdx.x;
  const int row = tid >> 2;        // 64 rows
  const int d0 = (tid & 3) * 16;   // 16 dims per thread

  float M = -1e30f;
#pragma unroll
  for (int s = 0; s < NSPLIT; ++s)
    M = fmaxf(M, pml[((h * NSPLIT + s) * 64 + row) * 2]);

  float L = 0.f;
  float o[16];
#pragma unroll
  for (int e = 0; e < 16; ++e) o[e] = 0.f;

#pragma unroll
  for (int s = 0; s < NSPLIT; ++s) {
    int b = ((h * NSPLIT + s) * 64 + row) * 2;
    float sc = __expf(pml[b] - M);
    L += pml[b + 1] * sc;
    const float4* a = (const float4*)(pacc + ((size_t)(h * NSPLIT + s) * 64 + row) * 64 + d0);
#pragma unroll
    for (int q4 = 0; q4 < 4; ++q4) {
      float4 av = a[q4];
      o[q4 * 4 + 0] += av.x * sc;
      o[q4 * 4 + 1] += av.y * sc;
      o[q4 * 4 + 2] += av.z * sc;
      o[q4 * 4 + 3] += av.w * sc;
    }
  }
  float inv = 1.f / L;
#pragma unroll
  for (int e = 0; e < 16; ++e)
    AO[(size_t)row * DMODEL + h * DKH + d0 + e] = f2bf(o[e] * inv);
}

// ---------------- launch ----------------
extern "C" void kernel_launch(void* const* d_in, const int* in_sizes, int n_in,
                              void* d_out, int out_size, void* d_ws, size_t ws_size,
                              hipStream_t stream) {
  const float* q   = (const float*)d_in[0];
  const float* k   = (const float*)d_in[1];
  const float* v   = (const float*)d_in[2];
  const float* w_q = (const float*)d_in[3];
  const float* b_q = (const float*)d_in[4];
  const float* w_k = (const float*)d_in[5];
  const float* b_k = (const float*)d_in[6];
  const float* w_v = (const float*)d_in[7];
  const float* b_v = (const float*)d_in[8];
  const float* w_o = (const float*)d_in[9];
  const float* b_o = (const float*)d_in[10];

  u16t* ws = (u16t*)d_ws;
  const size_t SZX = (size_t)S_LEN * DMODEL;
  const size_t SZW = (size_t)DMODEL * DMODEL;
  u16t* xb  = ws;
  u16t* wb0 = ws + SZX;
  u16t* wb1 = wb0 + SZW;
  u16t* wb2 = wb1 + SZW;
  u16t* wb3 = wb2 + SZW;
  u16t* Qp  = wb3 + SZW;
  u16t* Kp  = Qp + SZX;
  u16t* Vp  = Kp + SZX;
  u16t* AO  = Vp + SZX;
  // fp32 partials for global-q splits overlap xb (free during attention)
  float* pacc = (float*)xb;                               // 16*8*64*64 floats = 2 MB
  float* pml  = pacc + (size_t)NHEADS * NSPLIT * 64 * 64; // 16*8*64*2 floats

  dim3 blk(256);
  dim3 ggrid(DMODEL / BN, S_LEN / BM);
  const float scale = 0.125f;

  cvt_kernel<<<(int)(SZW / 1024), blk, 0, stream>>>(w_q, wb0, (int)SZW);
  cvt_kernel<<<(int)(SZW / 1024), blk, 0, stream>>>(w_k, wb1, (int)SZW);
  cvt_kernel<<<(int)(SZW / 1024), blk, 0, stream>>>(w_v, wb2, (int)SZW);
  cvt_kernel<<<(int)(SZW / 1024), blk, 0, stream>>>(w_o, wb3, (int)SZW);

  cvt_kernel<<<(int)(SZX / 1024), blk, 0, stream>>>(q, xb, (int)SZX);
  gemm_bt<0><<<ggrid, blk, 0, stream>>>(xb, wb0, b_q, Qp, S_LEN, DMODEL, DMODEL, scale);
  cvt_kernel<<<(int)(SZX / 1024), blk, 0, stream>>>(k, xb, (int)SZX);
  gemm_bt<0><<<ggrid, blk, 0, stream>>>(xb, wb1, b_k, Kp, S_LEN, DMODEL, DMODEL, 1.0f);
  cvt_kernel<<<(int)(SZX / 1024), blk, 0, stream>>>(v, xb, (int)SZX);
  gemm_bt<0><<<ggrid, blk, 0, stream>>>(xb, wb2, b_v, Vp, S_LEN, DMODEL, DMODEL, 1.0f);

  attn_kernel<<<dim3(63 + NSPLIT, NHEADS), blk, 0, stream>>>(Qp, Kp, Vp, AO, pacc, pml);
  merge_kernel<<<NHEADS, blk, 0, stream>>>(pacc, pml, AO);

  gemm_bt<1><<<ggrid, blk, 0, stream>>>(AO, wb3, b_o, d_out, S_LEN, DMODEL, DMODEL, 1.0f);
}

// Round 4
// 252.275 us; speedup vs baseline: 1.9657x; 1.1551x over previous
//
#include <hip/hip_runtime.h>

#define S_LEN 4096
#define DMODEL 1024
#define NHEADS 16
#define DKH 64
#define WIN 256
#define GTOK 64
#define NSPLIT 8

typedef unsigned short u16t;
typedef __attribute__((ext_vector_type(8))) short short8;
typedef __attribute__((ext_vector_type(4))) float f32x4;

__device__ __forceinline__ u16t f2bf(float x) {
  union { float f; unsigned int u; } v; v.f = x;
  unsigned int r = v.u + 0x7FFFu + ((v.u >> 16) & 1u);
  return (u16t)(r >> 16);
}

// ---------------- fused fp32 -> bf16 converts ----------------
// 4 weight matrices, each SZW = 2^20 elements
__global__ void cvt4_kernel(const float* __restrict__ s0, const float* __restrict__ s1,
                            const float* __restrict__ s2, const float* __restrict__ s3,
                            u16t* __restrict__ d0, u16t* __restrict__ d1,
                            u16t* __restrict__ d2, u16t* __restrict__ d3) {
  size_t i = (size_t)blockIdx.x * 1024 + threadIdx.x * 4;
  int which = (int)(i >> 20);
  size_t local = i & ((1u << 20) - 1);
  const float* s = which == 0 ? s0 : which == 1 ? s1 : which == 2 ? s2 : s3;
  u16t* d = which == 0 ? d0 : which == 1 ? d1 : which == 2 ? d2 : d3;
  float4 f = *(const float4*)(s + local);
  unsigned int lo = (unsigned int)f2bf(f.x) | ((unsigned int)f2bf(f.y) << 16);
  unsigned int hi = (unsigned int)f2bf(f.z) | ((unsigned int)f2bf(f.w) << 16);
  *(uint2*)(d + local) = make_uint2(lo, hi);
}

// 3 activation tensors, each SZX = 2^22 elements
__global__ void cvt3_kernel(const float* __restrict__ s0, const float* __restrict__ s1,
                            const float* __restrict__ s2,
                            u16t* __restrict__ d0, u16t* __restrict__ d1,
                            u16t* __restrict__ d2) {
  size_t i = (size_t)blockIdx.x * 1024 + threadIdx.x * 4;
  int which = (int)(i >> 22);
  size_t local = i & ((1u << 22) - 1);
  const float* s = which == 0 ? s0 : which == 1 ? s1 : s2;
  u16t* d = which == 0 ? d0 : which == 1 ? d1 : d2;
  float4 f = *(const float4*)(s + local);
  unsigned int lo = (unsigned int)f2bf(f.x) | ((unsigned int)f2bf(f.y) << 16);
  unsigned int hi = (unsigned int)f2bf(f.z) | ((unsigned int)f2bf(f.w) << 16);
  *(uint2*)(d + local) = make_uint2(lo, hi);
}

// ---------------- bf16 GEMM body: Y = A(M,K) @ B(N,K)^T + bias, * alpha ----------------
#define BN 128
#define BK 32
#define LDT 40

template<int OUT_F32, int BMT>
__device__ __forceinline__
void gemm_body(const u16t* __restrict__ A, const u16t* __restrict__ B,
               const float* __restrict__ bias, void* __restrict__ Y,
               int M, int N, int K, float alpha, int m0, int n0)
{
  constexpr int MF = BMT / 32;   // m-fragments per wave (4 or 2)
  constexpr int CA = BMT / 64;   // A staging chunks per thread (2 or 1)

  __shared__ __align__(16) u16t sA[BMT * LDT];
  __shared__ __align__(16) u16t sB[BN * LDT];

  const int tid = threadIdx.x;
  const int lane = tid & 63;
  const int lr = lane & 15, lg = lane >> 4;
  const int w = tid >> 6;
  const int wm = (w >> 1) * (MF * 16), wn = (w & 1) * 64;

  f32x4 acc[MF][4] = {};
  uint4 ra[CA], rb[2];

  const int nk = K / BK;

#pragma unroll
  for (int j = 0; j < CA; ++j) {
    int c = tid + j * 256, row = c >> 2, kb = c & 3;
    ra[j] = *(const uint4*)(A + (size_t)(m0 + row) * K + kb * 8);
  }
#pragma unroll
  for (int j = 0; j < 2; ++j) {
    int c = tid + j * 256, row = c >> 2, kb = c & 3;
    rb[j] = *(const uint4*)(B + (size_t)(n0 + row) * K + kb * 8);
  }
#pragma unroll
  for (int j = 0; j < CA; ++j) {
    int c = tid + j * 256, row = c >> 2, kb = c & 3;
    *(uint4*)&sA[row * LDT + kb * 8] = ra[j];
  }
#pragma unroll
  for (int j = 0; j < 2; ++j) {
    int c = tid + j * 256, row = c >> 2, kb = c & 3;
    *(uint4*)&sB[row * LDT + kb * 8] = rb[j];
  }
  __syncthreads();

  for (int kt = 0; kt < nk; ++kt) {
    if (kt + 1 < nk) {
#pragma unroll
      for (int j = 0; j < CA; ++j) {
        int c = tid + j * 256, row = c >> 2, kb = c & 3;
        ra[j] = *(const uint4*)(A + (size_t)(m0 + row) * K + (kt + 1) * BK + kb * 8);
      }
#pragma unroll
      for (int j = 0; j < 2; ++j) {
        int c = tid + j * 256, row = c >> 2, kb = c & 3;
        rb[j] = *(const uint4*)(B + (size_t)(n0 + row) * K + (kt + 1) * BK + kb * 8);
      }
    }
    short8 af[MF], bf[4];
#pragma unroll
    for (int mf = 0; mf < MF; ++mf)
      af[mf] = *(const short8*)&sA[(wm + mf * 16 + lr) * LDT + lg * 8];
#pragma unroll
    for (int nf = 0; nf < 4; ++nf)
      bf[nf] = *(const short8*)&sB[(wn + nf * 16 + lr) * LDT + lg * 8];
#pragma unroll
    for (int mf = 0; mf < MF; ++mf)
#pragma unroll
      for (int nf = 0; nf < 4; ++nf)
        acc[mf][nf] = __builtin_amdgcn_mfma_f32_16x16x32_bf16(af[mf], bf[nf], acc[mf][nf], 0, 0, 0);

    if (kt + 1 < nk) {
      __syncthreads();
#pragma unroll
      for (int j = 0; j < CA; ++j) {
        int c = tid + j * 256, row = c >> 2, kb = c & 3;
        *(uint4*)&sA[row * LDT + kb * 8] = ra[j];
      }
#pragma unroll
      for (int j = 0; j < 2; ++j) {
        int c = tid + j * 256, row = c >> 2, kb = c & 3;
        *(uint4*)&sB[row * LDT + kb * 8] = rb[j];
      }
      __syncthreads();
    }
  }

#pragma unroll
  for (int nf = 0; nf < 4; ++nf) {
    int col = n0 + wn + nf * 16 + lr;
    float bv = bias[col];
#pragma unroll
    for (int mf = 0; mf < MF; ++mf)
#pragma unroll
      for (int r = 0; r < 4; ++r) {
        int row = m0 + wm + mf * 16 + lg * 4 + r;
        float v = (acc[mf][nf][r] + bv) * alpha;
        if (OUT_F32) ((float*)Y)[(size_t)row * N + col] = v;
        else         ((u16t*)Y)[(size_t)row * N + col] = f2bf(v);
      }
  }
}

// fused Q/K/V projection: grid (8, 32, 3); z selects matrix -> 768 blocks co-resident
__global__ __launch_bounds__(256)
void gemm_qkv(const u16t* __restrict__ xq, const u16t* __restrict__ xk, const u16t* __restrict__ xv,
              const u16t* __restrict__ wq, const u16t* __restrict__ wk, const u16t* __restrict__ wv,
              const float* __restrict__ bq, const float* __restrict__ bk, const float* __restrict__ bv,
              u16t* __restrict__ Qp, u16t* __restrict__ Kp, u16t* __restrict__ Vp)
{
  const int z = blockIdx.z;
  const u16t* A = z == 0 ? xq : z == 1 ? xk : xv;
  const u16t* B = z == 0 ? wq : z == 1 ? wk : wv;
  const float* bi = z == 0 ? bq : z == 1 ? bk : bv;
  u16t* Y = z == 0 ? Qp : z == 1 ? Kp : Vp;
  const float alpha = (z == 0) ? 0.125f : 1.0f;
  gemm_body<0, 128>(A, B, bi, Y, S_LEN, DMODEL, DMODEL, alpha,
                    blockIdx.y * 128, blockIdx.x * BN);
}

// o-projection: BM=64 tile -> grid (8, 64) = 512 blocks, 2 blocks/CU
__global__ __launch_bounds__(256)
void gemm_o(const u16t* __restrict__ A, const u16t* __restrict__ B,
            const float* __restrict__ bias, float* __restrict__ Y)
{
  gemm_body<1, 64>(A, B, bias, Y, S_LEN, DMODEL, DMODEL, 1.0f,
                   blockIdx.y * 64, blockIdx.x * BN);
}

// ---------------- flash-style sparse attention ----------------
#define KLDT 72  // LDS row stride in u16 (144B)

// grid.x: 0..62 -> windowed blocks qb=1..63; 63..63+NSPLIT-1 -> global-q KV splits
__global__ __launch_bounds__(256)
void attn_kernel(const u16t* __restrict__ Qp, const u16t* __restrict__ Kp,
                 const u16t* __restrict__ Vp, u16t* __restrict__ AO,
                 float* __restrict__ pacc, float* __restrict__ pml)
{
  __shared__ __align__(16) u16t sK[64 * KLDT];
  __shared__ __align__(16) u16t sVt[64 * KLDT];
  __shared__ __align__(16) u16t sP[4][16 * KLDT];

  const int h = blockIdx.y;
  const int tid = threadIdx.x, w = tid >> 6, lane = tid & 63;
  const int lr = lane & 15, lg = lane >> 4;

  const bool windowed = (blockIdx.x < 63);
  const int qb = windowed ? (blockIdx.x + 1) : 0;
  const int split = windowed ? 0 : (blockIdx.x - 63);
  const int qw = qb * 64 + w * 16;

  short8 qf[2];
#pragma unroll
  for (int kk = 0; kk < 2; ++kk)
    qf[kk] = *(const short8*)(Qp + (size_t)(qw + lr) * DMODEL + h * DKH + kk * 32 + lg * 8);

  f32x4 acc[4] = {};
  float m_run[4], l_run[4];
#pragma unroll
  for (int r = 0; r < 4; ++r) { m_run[r] = -1e30f; l_run[r] = 0.f; }

  int lo = 1, nkv;
  if (windowed) {
    lo = (qb - 4 < 1) ? 1 : qb - 4;
    int hi = (qb + 4 > 63) ? 63 : qb + 4;
    nkv = hi - lo + 2;  // {0} ∪ [lo..hi]
  } else {
    nkv = 64 / NSPLIT;
  }

  uint4 rk[2], rv[2];

#define KVB(idx) (windowed ? ((idx) == 0 ? 0 : lo + (idx) - 1) : (split * (64 / NSPLIT) + (idx)))

  {
    int kv0 = KVB(0) * 64;
#pragma unroll
    for (int j = 0; j < 2; ++j) {
      int c = tid + j * 256, row = c >> 3, col8 = c & 7;
      rk[j] = *(const uint4*)(Kp + (size_t)(kv0 + row) * DMODEL + h * DKH + col8 * 8);
      rv[j] = *(const uint4*)(Vp + (size_t)(kv0 + row) * DMODEL + h * DKH + col8 * 8);
    }
#pragma unroll
    for (int j = 0; j < 2; ++j) {
      int c = tid + j * 256, row = c >> 3, col8 = c & 7;
      *(uint4*)&sK[row * KLDT + col8 * 8] = rk[j];
      union { uint4 u4; u16t s[8]; } uv; uv.u4 = rv[j];
#pragma unroll
      for (int e = 0; e < 8; ++e) {
        int d = col8 * 8 + e;
        sVt[d * KLDT + (row ^ ((d >> 3) << 3))] = uv.s[e];
      }
    }
  }
  __syncthreads();

  for (int idx = 0; idx < nkv; ++idx) {
    const int kv0 = KVB(idx) * 64;

    if (idx + 1 < nkv) {
      int nkv0 = KVB(idx + 1) * 64;
#pragma unroll
      for (int j = 0; j < 2; ++j) {
        int c = tid + j * 256, row = c >> 3, col8 = c & 7;
        rk[j] = *(const uint4*)(Kp + (size_t)(nkv0 + row) * DMODEL + h * DKH + col8 * 8);
        rv[j] = *(const uint4*)(Vp + (size_t)(nkv0 + row) * DMODEL + h * DKH + col8 * 8);
      }
    }

    f32x4 sacc[4] = {};
#pragma unroll
    for (int kk = 0; kk < 2; ++kk)
#pragma unroll
      for (int nf = 0; nf < 4; ++nf) {
        short8 kf = *(const short8*)&sK[(nf * 16 + lr) * KLDT + kk * 32 + lg * 8];
        sacc[nf] = __builtin_amdgcn_mfma_f32_16x16x32_bf16(qf[kk], kf, sacc[nf], 0, 0, 0);
      }

    if (windowed && kv0 > 0) {
#pragma unroll
      for (int r = 0; r < 4; ++r) {
        int qg = qw + lg * 4 + r;
#pragma unroll
        for (int nf = 0; nf < 4; ++nf) {
          int sg = kv0 + nf * 16 + lr;
          int diff = qg - sg; if (diff < 0) diff = -diff;
          if (diff > WIN) sacc[nf][r] = -1e30f;
        }
      }
    }

    float p[4][4];
#pragma unroll
    for (int r = 0; r < 4; ++r) {
      float rm = -1e30f;
#pragma unroll
      for (int nf = 0; nf < 4; ++nf) { p[nf][r] = sacc[nf][r]; rm = fmaxf(rm, p[nf][r]); }
#pragma unroll
      for (int off = 1; off < 16; off <<= 1) rm = fmaxf(rm, __shfl_xor(rm, off, 16));
      float mnew = fmaxf(m_run[r], rm);
      float corr = __expf(m_run[r] - mnew);
      m_run[r] = mnew;
      float rs = 0.f;
#pragma unroll
      for (int nf = 0; nf < 4; ++nf) {
        float e = __expf(p[nf][r] - mnew);
        p[nf][r] = e;
        rs += e;
      }
#pragma unroll
      for (int off = 1; off < 16; off <<= 1) rs += __shfl_xor(rs, off, 16);
      l_run[r] = l_run[r] * corr + rs;
#pragma unroll
      for (int nf = 0; nf < 4; ++nf) acc[nf][r] *= corr;
    }

#pragma unroll
    for (int nf = 0; nf < 4; ++nf)
#pragma unroll
      for (int r = 0; r < 4; ++r)
        sP[w][(lg * 4 + r) * KLDT + nf * 16 + lr] = f2bf(p[nf][r]);

#pragma unroll
    for (int kk = 0; kk < 2; ++kk) {
      short8 pf = *(const short8*)&sP[w][lr * KLDT + kk * 32 + lg * 8];
#pragma unroll
      for (int nf = 0; nf < 4; ++nf) {
        int d = nf * 16 + lr;
        int s0 = kk * 32 + lg * 8;
        short8 vf = *(const short8*)&sVt[d * KLDT + (s0 ^ ((d >> 3) << 3))];
        acc[nf] = __builtin_amdgcn_mfma_f32_16x16x32_bf16(pf, vf, acc[nf], 0, 0, 0);
      }
    }

    if (idx + 1 < nkv) {
      __syncthreads();
#pragma unroll
      for (int j = 0; j < 2; ++j) {
        int c = tid + j * 256, row = c >> 3, col8 = c & 7;
        *(uint4*)&sK[row * KLDT + col8 * 8] = rk[j];
        union { uint4 u4; u16t s[8]; } uv; uv.u4 = rv[j];
#pragma unroll
        for (int e = 0; e < 8; ++e) {
          int d = col8 * 8 + e;
          sVt[d * KLDT + (row ^ ((d >> 3) << 3))] = uv.s[e];
        }
      }
      __syncthreads();
    }
  }
#undef KVB

  if (windowed) {
#pragma unroll
    for (int nf = 0; nf < 4; ++nf)
#pragma unroll
      for (int r = 0; r < 4; ++r) {
        float v = acc[nf][r] / l_run[r];
        AO[(size_t)(qw + lg * 4 + r) * DMODEL + h * DKH + nf * 16 + lr] = f2bf(v);
      }
  } else {
    const int pbase = (h * NSPLIT + split) * 64;
#pragma unroll
    for (int nf = 0; nf < 4; ++nf)
#pragma unroll
      for (int r = 0; r < 4; ++r)
        pacc[(size_t)(pbase + w * 16 + lg * 4 + r) * 64 + nf * 16 + lr] = acc[nf][r];
    if (lr == 0) {
#pragma unroll
      for (int r = 0; r < 4; ++r) {
        int b = (pbase + w * 16 + lg * 4 + r) * 2;
        pml[b] = m_run[r];
        pml[b + 1] = l_run[r];
      }
    }
  }
}

// ---------------- merge partials for global q rows ----------------
__global__ __launch_bounds__(256)
void merge_kernel(const float* __restrict__ pacc, const float* __restrict__ pml,
                  u16t* __restrict__ AO)
{
  const int h = blockIdx.x;
  const int tid = threadIdx.x;
  const int row = tid >> 2;
  const int d0 = (tid & 3) * 16;

  float M = -1e30f;
#pragma unroll
  for (int s = 0; s < NSPLIT; ++s)
    M = fmaxf(M, pml[((h * NSPLIT + s) * 64 + row) * 2]);

  float L = 0.f;
  float o[16];
#pragma unroll
  for (int e = 0; e < 16; ++e) o[e] = 0.f;

#pragma unroll
  for (int s = 0; s < NSPLIT; ++s) {
    int b = ((h * NSPLIT + s) * 64 + row) * 2;
    float sc = __expf(pml[b] - M);
    L += pml[b + 1] * sc;
    const float4* a = (const float4*)(pacc + ((size_t)(h * NSPLIT + s) * 64 + row) * 64 + d0);
#pragma unroll
    for (int q4 = 0; q4 < 4; ++q4) {
      float4 av = a[q4];
      o[q4 * 4 + 0] += av.x * sc;
      o[q4 * 4 + 1] += av.y * sc;
      o[q4 * 4 + 2] += av.z * sc;
      o[q4 * 4 + 3] += av.w * sc;
    }
  }
  float inv = 1.f / L;
#pragma unroll
  for (int e = 0; e < 16; ++e)
    AO[(size_t)row * DMODEL + h * DKH + d0 + e] = f2bf(o[e] * inv);
}

// ---------------- launch ----------------
extern "C" void kernel_launch(void* const* d_in, const int* in_sizes, int n_in,
                              void* d_out, int out_size, void* d_ws, size_t ws_size,
                              hipStream_t stream) {
  const float* q   = (const float*)d_in[0];
  const float* k   = (const float*)d_in[1];
  const float* v   = (const float*)d_in[2];
  const float* w_q = (const float*)d_in[3];
  const float* b_q = (const float*)d_in[4];
  const float* w_k = (const float*)d_in[5];
  const float* b_k = (const float*)d_in[6];
  const float* w_v = (const float*)d_in[7];
  const float* b_v = (const float*)d_in[8];
  const float* w_o = (const float*)d_in[9];
  const float* b_o = (const float*)d_in[10];

  u16t* ws = (u16t*)d_ws;
  const size_t SZX = (size_t)S_LEN * DMODEL;   // 2^22
  const size_t SZW = (size_t)DMODEL * DMODEL;  // 2^20
  u16t* xq  = ws;
  u16t* xk  = xq + SZX;
  u16t* xv  = xk + SZX;
  u16t* wb0 = xv + SZX;
  u16t* wb1 = wb0 + SZW;
  u16t* wb2 = wb1 + SZW;
  u16t* wb3 = wb2 + SZW;
  u16t* Qp  = wb3 + SZW;
  u16t* Kp  = Qp + SZX;
  u16t* Vp  = Kp + SZX;
  // dead-buffer reuse after gemm_qkv: AO <- xk region, partials <- xq region
  u16t* AO  = xk;
  float* pacc = (float*)xq;                               // 2 MB
  float* pml  = pacc + (size_t)NHEADS * NSPLIT * 64 * 64;

  dim3 blk(256);

  cvt4_kernel<<<(int)(4 * SZW / 1024), blk, 0, stream>>>(w_q, w_k, w_v, w_o, wb0, wb1, wb2, wb3);
  cvt3_kernel<<<(int)(3 * SZX / 1024), blk, 0, stream>>>(q, k, v, xq, xk, xv);

  gemm_qkv<<<dim3(DMODEL / BN, S_LEN / 128, 3), blk, 0, stream>>>(
      xq, xk, xv, wb0, wb1, wb2, b_q, b_k, b_v, Qp, Kp, Vp);

  attn_kernel<<<dim3(63 + NSPLIT, NHEADS), blk, 0, stream>>>(Qp, Kp, Vp, AO, pacc, pml);
  merge_kernel<<<NHEADS, blk, 0, stream>>>(pacc, pml, AO);

  gemm_o<<<dim3(DMODEL / BN, S_LEN / 64), blk, 0, stream>>>(AO, wb3, b_o, (float*)d_out);
}

// Round 5
// 136.718 us; speedup vs baseline: 3.6272x; 1.8452x over previous
//
#include <hip/hip_runtime.h>

#define S_LEN 4096
#define DMODEL 1024
#define NHEADS 16
#define DKH 64
#define WIN 256
#define GTOK 64
#define NSPLIT 8

typedef unsigned short u16t;
typedef __attribute__((ext_vector_type(8))) short short8;
typedef __attribute__((ext_vector_type(4))) float f32x4;

__device__ __forceinline__ u16t f2bf(float x) {
  union { float f; unsigned int u; } v; v.f = x;
  unsigned int r = v.u + 0x7FFFu + ((v.u >> 16) & 1u);
  return (u16t)(r >> 16);
}

__device__ __forceinline__ void gload_lds16(const u16t* g, u16t* l) {
  __builtin_amdgcn_global_load_lds(
      (const __attribute__((address_space(1))) void*)g,
      (__attribute__((address_space(3))) void*)l, 16, 0, 0);
}

// ---------------- fused fp32 -> bf16 converts ----------------
__global__ void cvt4_kernel(const float* __restrict__ s0, const float* __restrict__ s1,
                            const float* __restrict__ s2, const float* __restrict__ s3,
                            u16t* __restrict__ d0, u16t* __restrict__ d1,
                            u16t* __restrict__ d2, u16t* __restrict__ d3) {
  size_t i = (size_t)blockIdx.x * 1024 + threadIdx.x * 4;
  int which = (int)(i >> 20);
  size_t local = i & ((1u << 20) - 1);
  const float* s = which == 0 ? s0 : which == 1 ? s1 : which == 2 ? s2 : s3;
  u16t* d = which == 0 ? d0 : which == 1 ? d1 : which == 2 ? d2 : d3;
  float4 f = *(const float4*)(s + local);
  unsigned int lo = (unsigned int)f2bf(f.x) | ((unsigned int)f2bf(f.y) << 16);
  unsigned int hi = (unsigned int)f2bf(f.z) | ((unsigned int)f2bf(f.w) << 16);
  *(uint2*)(d + local) = make_uint2(lo, hi);
}

__global__ void cvt3_kernel(const float* __restrict__ s0, const float* __restrict__ s1,
                            const float* __restrict__ s2,
                            u16t* __restrict__ d0, u16t* __restrict__ d1,
                            u16t* __restrict__ d2) {
  size_t i = (size_t)blockIdx.x * 1024 + threadIdx.x * 4;
  int which = (int)(i >> 22);
  size_t local = i & ((1u << 22) - 1);
  const float* s = which == 0 ? s0 : which == 1 ? s1 : s2;
  u16t* d = which == 0 ? d0 : which == 1 ? d1 : d2;
  float4 f = *(const float4*)(s + local);
  unsigned int lo = (unsigned int)f2bf(f.x) | ((unsigned int)f2bf(f.y) << 16);
  unsigned int hi = (unsigned int)f2bf(f.z) | ((unsigned int)f2bf(f.w) << 16);
  *(uint2*)(d + local) = make_uint2(lo, hi);
}

// ---------------- bf16 GEMM body (m97 structure): Y = A @ B^T + bias, * alpha ----
// BK=64; LDS linear; global-source XOR pre-swizzle, XOR on ds_read (rule 21).
#define BN 128
#define GBK 64

template<int OUT_F32, int BMT>
__device__ __forceinline__
void gemm_body(const u16t* __restrict__ A, const u16t* __restrict__ B,
               const float* __restrict__ bias, void* __restrict__ Y,
               int N, int K, float alpha, int m0, int n0)
{
  constexpr int MF = BMT / 32;          // m-fragments per wave (4 or 2)
  constexpr int CA_ISS = BMT * 2 / 64;  // gload issues per wave for sA (4 or 2)

  __shared__ __align__(16) u16t sA[BMT * GBK];
  __shared__ __align__(16) u16t sB[BN * GBK];

  const int tid = threadIdx.x;
  const int lane = tid & 63;
  const int lr = lane & 15, lg = lane >> 4;
  const int w = tid >> 6;
  const int wm = (w >> 1) * (MF * 16), wn = (w & 1) * 64;

  f32x4 acc[MF][4] = {};
  const int nk = K / GBK;

  for (int kt = 0; kt < nk; ++kt) {
    if (kt) __syncthreads();  // all waves done reading previous tile
    // stage tile kt: LDS slot (row, s) <- global (row, s ^ (row&7))
#pragma unroll
    for (int i = 0; i < CA_ISS; ++i) {
      int c0 = w * (BMT * 2) + i * 64;
      int c = c0 + lane;
      int row = c >> 3, g = (c & 7) ^ (row & 7);
      gload_lds16(A + (size_t)(m0 + row) * K + kt * GBK + g * 8, sA + (size_t)c0 * 8);
    }
#pragma unroll
    for (int i = 0; i < 4; ++i) {
      int c0 = w * 256 + i * 64;
      int c = c0 + lane;
      int row = c >> 3, g = (c & 7) ^ (row & 7);
      gload_lds16(B + (size_t)(n0 + row) * K + kt * GBK + g * 8, sB + (size_t)c0 * 8);
    }
    __syncthreads();  // vmcnt drained before barrier -> tile staged

    short8 af[MF][2], bf[4][2];
#pragma unroll
    for (int mf = 0; mf < MF; ++mf)
#pragma unroll
      for (int kk = 0; kk < 2; ++kk) {
        int s = ((kk * 4 + lg) ^ (lr & 7));
        af[mf][kk] = *(const short8*)&sA[(wm + mf * 16 + lr) * GBK + s * 8];
      }
#pragma unroll
    for (int nf = 0; nf < 4; ++nf)
#pragma unroll
      for (int kk = 0; kk < 2; ++kk) {
        int s = ((kk * 4 + lg) ^ (lr & 7));
        bf[nf][kk] = *(const short8*)&sB[(wn + nf * 16 + lr) * GBK + s * 8];
      }
#pragma unroll
    for (int kk = 0; kk < 2; ++kk)
#pragma unroll
      for (int mf = 0; mf < MF; ++mf)
#pragma unroll
        for (int nf = 0; nf < 4; ++nf)
          acc[mf][nf] = __builtin_amdgcn_mfma_f32_16x16x32_bf16(af[mf][kk], bf[nf][kk], acc[mf][nf], 0, 0, 0);
  }

#pragma unroll
  for (int nf = 0; nf < 4; ++nf) {
    int col = n0 + wn + nf * 16 + lr;
    float bv = bias[col];
#pragma unroll
    for (int mf = 0; mf < MF; ++mf)
#pragma unroll
      for (int r = 0; r < 4; ++r) {
        int row = m0 + wm + mf * 16 + lg * 4 + r;
        float v = (acc[mf][nf][r] + bv) * alpha;
        if (OUT_F32) ((float*)Y)[(size_t)row * N + col] = v;
        else         ((u16t*)Y)[(size_t)row * N + col] = f2bf(v);
      }
  }
}

// fused Q/K/V projection: 768 blocks (1D), bijective XCD swizzle (96 blocks/XCD)
__global__ __launch_bounds__(256)
void gemm_qkv(const u16t* __restrict__ xq, const u16t* __restrict__ xk, const u16t* __restrict__ xv,
              const u16t* __restrict__ wq, const u16t* __restrict__ wk, const u16t* __restrict__ wv,
              const float* __restrict__ bq, const float* __restrict__ bk, const float* __restrict__ bv,
              u16t* __restrict__ Qp, u16t* __restrict__ Kp, u16t* __restrict__ Vp)
{
  int b = blockIdx.x;
  int wid = (b & 7) * 96 + (b >> 3);   // XCD x gets contiguous work ids [x*96, x*96+96)
  int z = wid >> 8;                    // matrix (256 work ids each)
  int rem = wid & 255;
  int my = rem >> 3, mx = rem & 7;     // consecutive ids share the A m-panel
  const u16t* A = z == 0 ? xq : z == 1 ? xk : xv;
  const u16t* B = z == 0 ? wq : z == 1 ? wk : wv;
  const float* bi = z == 0 ? bq : z == 1 ? bk : bv;
  u16t* Y = z == 0 ? Qp : z == 1 ? Kp : Vp;
  const float alpha = (z == 0) ? 0.125f : 1.0f;
  gemm_body<0, 128>(A, B, bi, Y, DMODEL, DMODEL, alpha, my * 128, mx * BN);
}

// o-projection: BM=64 tile -> 512 blocks (1D), XCD swizzle (64 blocks/XCD)
__global__ __launch_bounds__(256)
void gemm_o(const u16t* __restrict__ A, const u16t* __restrict__ B,
            const float* __restrict__ bias, float* __restrict__ Y)
{
  int b = blockIdx.x;
  int wid = (b & 7) * 64 + (b >> 3);
  int my = wid >> 3, mx = wid & 7;
  gemm_body<1, 64>(A, B, bias, Y, DMODEL, DMODEL, 1.0f, my * 64, mx * BN);
}

// ---------------- flash-style sparse attention ----------------
#define KLDT 72  // LDS row stride in u16 (144B)

__global__ __launch_bounds__(256)
void attn_kernel(const u16t* __restrict__ Qp, const u16t* __restrict__ Kp,
                 const u16t* __restrict__ Vp, u16t* __restrict__ AO,
                 float* __restrict__ pacc, float* __restrict__ pml)
{
  __shared__ __align__(16) u16t sK[64 * KLDT];
  __shared__ __align__(16) u16t sVt[64 * KLDT];
  __shared__ __align__(16) u16t sP[4][16 * KLDT];

  const int h = blockIdx.y;
  const int tid = threadIdx.x, w = tid >> 6, lane = tid & 63;
  const int lr = lane & 15, lg = lane >> 4;

  const bool windowed = (blockIdx.x < 63);
  const int qb = windowed ? (blockIdx.x + 1) : 0;
  const int split = windowed ? 0 : (blockIdx.x - 63);
  const int qw = qb * 64 + w * 16;

  short8 qf[2];
#pragma unroll
  for (int kk = 0; kk < 2; ++kk)
    qf[kk] = *(const short8*)(Qp + (size_t)(qw + lr) * DMODEL + h * DKH + kk * 32 + lg * 8);

  f32x4 acc[4] = {};
  float m_run[4], l_run[4];
#pragma unroll
  for (int r = 0; r < 4; ++r) { m_run[r] = -1e30f; l_run[r] = 0.f; }

  int lo = 1, nkv;
  if (windowed) {
    lo = (qb - 4 < 1) ? 1 : qb - 4;
    int hi = (qb + 4 > 63) ? 63 : qb + 4;
    nkv = hi - lo + 2;  // {0} ∪ [lo..hi]
  } else {
    nkv = 64 / NSPLIT;
  }

  uint4 rk[2], rv[2];

#define KVB(idx) (windowed ? ((idx) == 0 ? 0 : lo + (idx) - 1) : (split * (64 / NSPLIT) + (idx)))

  {
    int kv0 = KVB(0) * 64;
#pragma unroll
    for (int j = 0; j < 2; ++j) {
      int c = tid + j * 256, row = c >> 3, col8 = c & 7;
      rk[j] = *(const uint4*)(Kp + (size_t)(kv0 + row) * DMODEL + h * DKH + col8 * 8);
      rv[j] = *(const uint4*)(Vp + (size_t)(kv0 + row) * DMODEL + h * DKH + col8 * 8);
    }
#pragma unroll
    for (int j = 0; j < 2; ++j) {
      int c = tid + j * 256, row = c >> 3, col8 = c & 7;
      *(uint4*)&sK[row * KLDT + col8 * 8] = rk[j];
      union { uint4 u4; u16t s[8]; } uv; uv.u4 = rv[j];
#pragma unroll
      for (int e = 0; e < 8; ++e) {
        int d = col8 * 8 + e;
        sVt[d * KLDT + (row ^ ((d >> 3) << 3))] = uv.s[e];
      }
    }
  }
  __syncthreads();

  for (int idx = 0; idx < nkv; ++idx) {
    const int kv0 = KVB(idx) * 64;

    if (idx + 1 < nkv) {
      int nkv0 = KVB(idx + 1) * 64;
#pragma unroll
      for (int j = 0; j < 2; ++j) {
        int c = tid + j * 256, row = c >> 3, col8 = c & 7;
        rk[j] = *(const uint4*)(Kp + (size_t)(nkv0 + row) * DMODEL + h * DKH + col8 * 8);
        rv[j] = *(const uint4*)(Vp + (size_t)(nkv0 + row) * DMODEL + h * DKH + col8 * 8);
      }
    }

    f32x4 sacc[4] = {};
#pragma unroll
    for (int kk = 0; kk < 2; ++kk)
#pragma unroll
      for (int nf = 0; nf < 4; ++nf) {
        short8 kf = *(const short8*)&sK[(nf * 16 + lr) * KLDT + kk * 32 + lg * 8];
        sacc[nf] = __builtin_amdgcn_mfma_f32_16x16x32_bf16(qf[kk], kf, sacc[nf], 0, 0, 0);
      }

    if (windowed && kv0 > 0) {
#pragma unroll
      for (int r = 0; r < 4; ++r) {
        int qg = qw + lg * 4 + r;
#pragma unroll
        for (int nf = 0; nf < 4; ++nf) {
          int sg = kv0 + nf * 16 + lr;
          int diff = qg - sg; if (diff < 0) diff = -diff;
          if (diff > WIN) sacc[nf][r] = -1e30f;
        }
      }
    }

    float p[4][4];
#pragma unroll
    for (int r = 0; r < 4; ++r) {
      float rm = -1e30f;
#pragma unroll
      for (int nf = 0; nf < 4; ++nf) { p[nf][r] = sacc[nf][r]; rm = fmaxf(rm, p[nf][r]); }
#pragma unroll
      for (int off = 1; off < 16; off <<= 1) rm = fmaxf(rm, __shfl_xor(rm, off, 16));
      float mnew = fmaxf(m_run[r], rm);
      float corr = __expf(m_run[r] - mnew);
      m_run[r] = mnew;
      float rs = 0.f;
#pragma unroll
      for (int nf = 0; nf < 4; ++nf) {
        float e = __expf(p[nf][r] - mnew);
        p[nf][r] = e;
        rs += e;
      }
#pragma unroll
      for (int off = 1; off < 16; off <<= 1) rs += __shfl_xor(rs, off, 16);
      l_run[r] = l_run[r] * corr + rs;
#pragma unroll
      for (int nf = 0; nf < 4; ++nf) acc[nf][r] *= corr;
    }

#pragma unroll
    for (int nf = 0; nf < 4; ++nf)
#pragma unroll
      for (int r = 0; r < 4; ++r)
        sP[w][(lg * 4 + r) * KLDT + nf * 16 + lr] = f2bf(p[nf][r]);

#pragma unroll
    for (int kk = 0; kk < 2; ++kk) {
      short8 pf = *(const short8*)&sP[w][lr * KLDT + kk * 32 + lg * 8];
#pragma unroll
      for (int nf = 0; nf < 4; ++nf) {
        int d = nf * 16 + lr;
        int s0 = kk * 32 + lg * 8;
        short8 vf = *(const short8*)&sVt[d * KLDT + (s0 ^ ((d >> 3) << 3))];
        acc[nf] = __builtin_amdgcn_mfma_f32_16x16x32_bf16(pf, vf, acc[nf], 0, 0, 0);
      }
    }

    if (idx + 1 < nkv) {
      __syncthreads();
#pragma unroll
      for (int j = 0; j < 2; ++j) {
        int c = tid + j * 256, row = c >> 3, col8 = c & 7;
        *(uint4*)&sK[row * KLDT + col8 * 8] = rk[j];
        union { uint4 u4; u16t s[8]; } uv; uv.u4 = rv[j];
#pragma unroll
        for (int e = 0; e < 8; ++e) {
          int d = col8 * 8 + e;
          sVt[d * KLDT + (row ^ ((d >> 3) << 3))] = uv.s[e];
        }
      }
      __syncthreads();
    }
  }
#undef KVB

  if (windowed) {
#pragma unroll
    for (int nf = 0; nf < 4; ++nf)
#pragma unroll
      for (int r = 0; r < 4; ++r) {
        float v = acc[nf][r] / l_run[r];
        AO[(size_t)(qw + lg * 4 + r) * DMODEL + h * DKH + nf * 16 + lr] = f2bf(v);
      }
  } else {
    const int pbase = (h * NSPLIT + split) * 64;
#pragma unroll
    for (int nf = 0; nf < 4; ++nf)
#pragma unroll
      for (int r = 0; r < 4; ++r)
        pacc[(size_t)(pbase + w * 16 + lg * 4 + r) * 64 + nf * 16 + lr] = acc[nf][r];
    if (lr == 0) {
#pragma unroll
      for (int r = 0; r < 4; ++r) {
        int b = (pbase + w * 16 + lg * 4 + r) * 2;
        pml[b] = m_run[r];
        pml[b + 1] = l_run[r];
      }
    }
  }
}

// ---------------- merge partials for global q rows ----------------
__global__ __launch_bounds__(256)
void merge_kernel(const float* __restrict__ pacc, const float* __restrict__ pml,
                  u16t* __restrict__ AO)
{
  const int h = blockIdx.x;
  const int tid = threadIdx.x;
  const int row = tid >> 2;
  const int d0 = (tid & 3) * 16;

  float M = -1e30f;
#pragma unroll
  for (int s = 0; s < NSPLIT; ++s)
    M = fmaxf(M, pml[((h * NSPLIT + s) * 64 + row) * 2]);

  float L = 0.f;
  float o[16];
#pragma unroll
  for (int e = 0; e < 16; ++e) o[e] = 0.f;

#pragma unroll
  for (int s = 0; s < NSPLIT; ++s) {
    int b = ((h * NSPLIT + s) * 64 + row) * 2;
    float sc = __expf(pml[b] - M);
    L += pml[b + 1] * sc;
    const float4* a = (const float4*)(pacc + ((size_t)(h * NSPLIT + s) * 64 + row) * 64 + d0);
#pragma unroll
    for (int q4 = 0; q4 < 4; ++q4) {
      float4 av = a[q4];
      o[q4 * 4 + 0] += av.x * sc;
      o[q4 * 4 + 1] += av.y * sc;
      o[q4 * 4 + 2] += av.z * sc;
      o[q4 * 4 + 3] += av.w * sc;
    }
  }
  float inv = 1.f / L;
#pragma unroll
  for (int e = 0; e < 16; ++e)
    AO[(size_t)row * DMODEL + h * DKH + d0 + e] = f2bf(o[e] * inv);
}

// ---------------- launch ----------------
extern "C" void kernel_launch(void* const* d_in, const int* in_sizes, int n_in,
                              void* d_out, int out_size, void* d_ws, size_t ws_size,
                              hipStream_t stream) {
  const float* q   = (const float*)d_in[0];
  const float* k   = (const float*)d_in[1];
  const float* v   = (const float*)d_in[2];
  const float* w_q = (const float*)d_in[3];
  const float* b_q = (const float*)d_in[4];
  const float* w_k = (const float*)d_in[5];
  const float* b_k = (const float*)d_in[6];
  const float* w_v = (const float*)d_in[7];
  const float* b_v = (const float*)d_in[8];
  const float* w_o = (const float*)d_in[9];
  const float* b_o = (const float*)d_in[10];

  u16t* ws = (u16t*)d_ws;
  const size_t SZX = (size_t)S_LEN * DMODEL;   // 2^22
  const size_t SZW = (size_t)DMODEL * DMODEL;  // 2^20
  u16t* xq  = ws;
  u16t* xk  = xq + SZX;
  u16t* xv  = xk + SZX;
  u16t* wb0 = xv + SZX;
  u16t* wb1 = wb0 + SZW;
  u16t* wb2 = wb1 + SZW;
  u16t* wb3 = wb2 + SZW;
  u16t* Qp  = wb3 + SZW;
  u16t* Kp  = Qp + SZX;
  u16t* Vp  = Kp + SZX;
  // dead-buffer reuse after gemm_qkv: AO <- xk region, partials <- xq region
  u16t* AO  = xk;
  float* pacc = (float*)xq;
  float* pml  = pacc + (size_t)NHEADS * NSPLIT * 64 * 64;

  dim3 blk(256);

  cvt4_kernel<<<(int)(4 * SZW / 1024), blk, 0, stream>>>(w_q, w_k, w_v, w_o, wb0, wb1, wb2, wb3);
  cvt3_kernel<<<(int)(3 * SZX / 1024), blk, 0, stream>>>(q, k, v, xq, xk, xv);

  gemm_qkv<<<768, blk, 0, stream>>>(xq, xk, xv, wb0, wb1, wb2, b_q, b_k, b_v, Qp, Kp, Vp);

  attn_kernel<<<dim3(63 + NSPLIT, NHEADS), blk, 0, stream>>>(Qp, Kp, Vp, AO, pacc, pml);
  merge_kernel<<<NHEADS, blk, 0, stream>>>(pacc, pml, AO);

  gemm_o<<<512, blk, 0, stream>>>(AO, wb3, b_o, (float*)d_out);
}

// Round 6
// 129.645 us; speedup vs baseline: 3.8251x; 1.0546x over previous
//
#include <hip/hip_runtime.h>

#define S_LEN 4096
#define DMODEL 1024
#define NHEADS 16
#define DKH 64
#define WIN 256
#define GTOK 64
#define NSPLIT 8

typedef unsigned short u16t;
typedef __attribute__((ext_vector_type(8))) short short8;
typedef __attribute__((ext_vector_type(4))) float f32x4;

__device__ __forceinline__ u16t f2bf(float x) {
  union { float f; unsigned int u; } v; v.f = x;
  unsigned int r = v.u + 0x7FFFu + ((v.u >> 16) & 1u);
  return (u16t)(r >> 16);
}

__device__ __forceinline__ void gload_lds16(const u16t* g, u16t* l) {
  __builtin_amdgcn_global_load_lds(
      (const __attribute__((address_space(1))) void*)g,
      (__attribute__((address_space(3))) void*)l, 16, 0, 0);
}

// ---------------- fused fp32 -> bf16 converts ----------------
__global__ void cvt4_kernel(const float* __restrict__ s0, const float* __restrict__ s1,
                            const float* __restrict__ s2, const float* __restrict__ s3,
                            u16t* __restrict__ d0, u16t* __restrict__ d1,
                            u16t* __restrict__ d2, u16t* __restrict__ d3) {
  size_t i = (size_t)blockIdx.x * 1024 + threadIdx.x * 4;
  int which = (int)(i >> 20);
  size_t local = i & ((1u << 20) - 1);
  const float* s = which == 0 ? s0 : which == 1 ? s1 : which == 2 ? s2 : s3;
  u16t* d = which == 0 ? d0 : which == 1 ? d1 : which == 2 ? d2 : d3;
  float4 f = *(const float4*)(s + local);
  unsigned int lo = (unsigned int)f2bf(f.x) | ((unsigned int)f2bf(f.y) << 16);
  unsigned int hi = (unsigned int)f2bf(f.z) | ((unsigned int)f2bf(f.w) << 16);
  *(uint2*)(d + local) = make_uint2(lo, hi);
}

__global__ void cvt3_kernel(const float* __restrict__ s0, const float* __restrict__ s1,
                            const float* __restrict__ s2,
                            u16t* __restrict__ d0, u16t* __restrict__ d1,
                            u16t* __restrict__ d2) {
  size_t i = (size_t)blockIdx.x * 1024 + threadIdx.x * 4;
  int which = (int)(i >> 22);
  size_t local = i & ((1u << 22) - 1);
  const float* s = which == 0 ? s0 : which == 1 ? s1 : s2;
  u16t* d = which == 0 ? d0 : which == 1 ? d1 : d2;
  float4 f = *(const float4*)(s + local);
  unsigned int lo = (unsigned int)f2bf(f.x) | ((unsigned int)f2bf(f.y) << 16);
  unsigned int hi = (unsigned int)f2bf(f.z) | ((unsigned int)f2bf(f.w) << 16);
  *(uint2*)(d + local) = make_uint2(lo, hi);
}

// ---------------- bf16 GEMM body (m97 structure): Y = A @ B^T + bias, * alpha ----
#define BN 128
#define GBK 64

template<int OUT_F32, int BMT>
__device__ __forceinline__
void gemm_body(const u16t* __restrict__ A, const u16t* __restrict__ B,
               const float* __restrict__ bias, void* __restrict__ Y,
               int N, int K, float alpha, int m0, int n0)
{
  constexpr int MF = BMT / 32;
  constexpr int CA_ISS = BMT * 2 / 64;

  __shared__ __align__(16) u16t sA[BMT * GBK];
  __shared__ __align__(16) u16t sB[BN * GBK];

  const int tid = threadIdx.x;
  const int lane = tid & 63;
  const int lr = lane & 15, lg = lane >> 4;
  const int w = tid >> 6;
  const int wm = (w >> 1) * (MF * 16), wn = (w & 1) * 64;

  f32x4 acc[MF][4] = {};
  const int nk = K / GBK;

  for (int kt = 0; kt < nk; ++kt) {
    if (kt) __syncthreads();
#pragma unroll
    for (int i = 0; i < CA_ISS; ++i) {
      int c0 = w * (BMT * 2) + i * 64;
      int c = c0 + lane;
      int row = c >> 3, g = (c & 7) ^ (row & 7);
      gload_lds16(A + (size_t)(m0 + row) * K + kt * GBK + g * 8, sA + (size_t)c0 * 8);
    }
#pragma unroll
    for (int i = 0; i < 4; ++i) {
      int c0 = w * 256 + i * 64;
      int c = c0 + lane;
      int row = c >> 3, g = (c & 7) ^ (row & 7);
      gload_lds16(B + (size_t)(n0 + row) * K + kt * GBK + g * 8, sB + (size_t)c0 * 8);
    }
    __syncthreads();

    short8 af[MF][2], bf[4][2];
#pragma unroll
    for (int mf = 0; mf < MF; ++mf)
#pragma unroll
      for (int kk = 0; kk < 2; ++kk) {
        int s = ((kk * 4 + lg) ^ (lr & 7));
        af[mf][kk] = *(const short8*)&sA[(wm + mf * 16 + lr) * GBK + s * 8];
      }
#pragma unroll
    for (int nf = 0; nf < 4; ++nf)
#pragma unroll
      for (int kk = 0; kk < 2; ++kk) {
        int s = ((kk * 4 + lg) ^ (lr & 7));
        bf[nf][kk] = *(const short8*)&sB[(wn + nf * 16 + lr) * GBK + s * 8];
      }
#pragma unroll
    for (int kk = 0; kk < 2; ++kk)
#pragma unroll
      for (int mf = 0; mf < MF; ++mf)
#pragma unroll
        for (int nf = 0; nf < 4; ++nf)
          acc[mf][nf] = __builtin_amdgcn_mfma_f32_16x16x32_bf16(af[mf][kk], bf[nf][kk], acc[mf][nf], 0, 0, 0);
  }

#pragma unroll
  for (int nf = 0; nf < 4; ++nf) {
    int col = n0 + wn + nf * 16 + lr;
    float bv = bias[col];
#pragma unroll
    for (int mf = 0; mf < MF; ++mf)
#pragma unroll
      for (int r = 0; r < 4; ++r) {
        int row = m0 + wm + mf * 16 + lg * 4 + r;
        float v = (acc[mf][nf][r] + bv) * alpha;
        if (OUT_F32) ((float*)Y)[(size_t)row * N + col] = v;
        else         ((u16t*)Y)[(size_t)row * N + col] = f2bf(v);
      }
  }
}

// fused Q/K/V projection: 768 blocks (1D), bijective XCD swizzle (96 blocks/XCD)
// Q is scaled by 1/sqrt(dk) * log2(e) so attention softmax runs in exp2 domain.
#define QSCALE 0.18033688011112042f
__global__ __launch_bounds__(256)
void gemm_qkv(const u16t* __restrict__ xq, const u16t* __restrict__ xk, const u16t* __restrict__ xv,
              const u16t* __restrict__ wq, const u16t* __restrict__ wk, const u16t* __restrict__ wv,
              const float* __restrict__ bq, const float* __restrict__ bk, const float* __restrict__ bv,
              u16t* __restrict__ Qp, u16t* __restrict__ Kp, u16t* __restrict__ Vp)
{
  int b = blockIdx.x;
  int wid = (b & 7) * 96 + (b >> 3);
  int z = wid >> 8;
  int rem = wid & 255;
  int my = rem >> 3, mx = rem & 7;
  const u16t* A = z == 0 ? xq : z == 1 ? xk : xv;
  const u16t* B = z == 0 ? wq : z == 1 ? wk : wv;
  const float* bi = z == 0 ? bq : z == 1 ? bk : bv;
  u16t* Y = z == 0 ? Qp : z == 1 ? Kp : Vp;
  const float alpha = (z == 0) ? QSCALE : 1.0f;
  gemm_body<0, 128>(A, B, bi, Y, DMODEL, DMODEL, alpha, my * 128, mx * BN);
}

__global__ __launch_bounds__(256)
void gemm_o(const u16t* __restrict__ A, const u16t* __restrict__ B,
            const float* __restrict__ bias, float* __restrict__ Y)
{
  int b = blockIdx.x;
  int wid = (b & 7) * 64 + (b >> 3);
  int my = wid >> 3, mx = wid & 7;
  gemm_body<1, 64>(A, B, bias, Y, DMODEL, DMODEL, 1.0f, my * 64, mx * BN);
}

// ---------------- flash-style sparse attention (swapped QK^T) ----------------
#define KLDT 72  // LDS row stride in u16 (144B)

__global__ __launch_bounds__(256)
void attn_kernel(const u16t* __restrict__ Qp, const u16t* __restrict__ Kp,
                 const u16t* __restrict__ Vp, u16t* __restrict__ AO,
                 float* __restrict__ pacc, float* __restrict__ pml)
{
  __shared__ __align__(16) u16t sK[64 * KLDT];
  __shared__ __align__(16) u16t sVt[64 * KLDT];
  __shared__ __align__(16) u16t sP[4][16 * KLDT];

  const int h = blockIdx.y;
  const int tid = threadIdx.x, w = tid >> 6, lane = tid & 63;
  const int lr = lane & 15, lg = lane >> 4;

  const bool windowed = (blockIdx.x < 63);
  const int qb = windowed ? (blockIdx.x + 1) : 0;
  const int split = windowed ? 0 : (blockIdx.x - 63);
  const int qw = qb * 64 + w * 16;

  short8 qf[2];
#pragma unroll
  for (int kk = 0; kk < 2; ++kk)
    qf[kk] = *(const short8*)(Qp + (size_t)(qw + lr) * DMODEL + h * DKH + kk * 32 + lg * 8);

  f32x4 acc[4] = {};
  float m_run = -1e30f, l_run = 0.f;  // per-lane scalars: this lane's q row is qw+lr

  int lo = 1, nkv;
  if (windowed) {
    lo = (qb - 4 < 1) ? 1 : qb - 4;
    int hi = (qb + 4 > 63) ? 63 : qb + 4;
    nkv = hi - lo + 2;  // {0} ∪ [lo..hi]
  } else {
    nkv = 64 / NSPLIT;
  }

  uint4 rk[2], rv[2];

#define KVB(idx) (windowed ? ((idx) == 0 ? 0 : lo + (idx) - 1) : (split * (64 / NSPLIT) + (idx)))

  {
    int kv0 = KVB(0) * 64;
#pragma unroll
    for (int j = 0; j < 2; ++j) {
      int c = tid + j * 256, row = c >> 3, col8 = c & 7;
      rk[j] = *(const uint4*)(Kp + (size_t)(kv0 + row) * DMODEL + h * DKH + col8 * 8);
      rv[j] = *(const uint4*)(Vp + (size_t)(kv0 + row) * DMODEL + h * DKH + col8 * 8);
    }
#pragma unroll
    for (int j = 0; j < 2; ++j) {
      int c = tid + j * 256, row = c >> 3, col8 = c & 7;
      *(uint4*)&sK[row * KLDT + col8 * 8] = rk[j];
      union { uint4 u4; u16t s[8]; } uv; uv.u4 = rv[j];
#pragma unroll
      for (int e = 0; e < 8; ++e) {
        int d = col8 * 8 + e;
        sVt[d * KLDT + (row ^ ((d >> 3) << 3))] = uv.s[e];
      }
    }
  }
  __syncthreads();

  for (int idx = 0; idx < nkv; ++idx) {
    const int kv0 = KVB(idx) * 64;

    if (idx + 1 < nkv) {
      int nkv0 = KVB(idx + 1) * 64;
#pragma unroll
      for (int j = 0; j < 2; ++j) {
        int c = tid + j * 256, row = c >> 3, col8 = c & 7;
        rk[j] = *(const uint4*)(Kp + (size_t)(nkv0 + row) * DMODEL + h * DKH + col8 * 8);
        rv[j] = *(const uint4*)(Vp + (size_t)(nkv0 + row) * DMODEL + h * DKH + col8 * 8);
      }
    }

    // S^T = K Q^T: sacc[nf][r] = S[k = kv0 + nf*16 + lg*4 + r][q = qw + lr]
    f32x4 sacc[4] = {};
#pragma unroll
    for (int kk = 0; kk < 2; ++kk)
#pragma unroll
      for (int nf = 0; nf < 4; ++nf) {
        short8 kf = *(const short8*)&sK[(nf * 16 + lr) * KLDT + kk * 32 + lg * 8];
        sacc[nf] = __builtin_amdgcn_mfma_f32_16x16x32_bf16(kf, qf[kk], sacc[nf], 0, 0, 0);
      }

    if (windowed && kv0 > 0) {
      int qg = qw + lr;
#pragma unroll
      for (int nf = 0; nf < 4; ++nf)
#pragma unroll
        for (int r = 0; r < 4; ++r) {
          int sg = kv0 + nf * 16 + lg * 4 + r;
          int diff = qg - sg; if (diff < 0) diff = -diff;
          if (diff > WIN) sacc[nf][r] = -1e30f;
        }
    }

    // online softmax in exp2 domain (S pre-scaled by log2e): lane owns q = qw+lr
    float rm = sacc[0][0];
#pragma unroll
    for (int nf = 0; nf < 4; ++nf)
#pragma unroll
      for (int r = 0; r < 4; ++r)
        rm = fmaxf(rm, sacc[nf][r]);
    rm = fmaxf(rm, __shfl_xor(rm, 16));
    rm = fmaxf(rm, __shfl_xor(rm, 32));
    float mnew = fmaxf(m_run, rm);
    float corr = exp2f(m_run - mnew);
    m_run = mnew;

    float p[4][4];
    float rs = 0.f;
#pragma unroll
    for (int nf = 0; nf < 4; ++nf)
#pragma unroll
      for (int r = 0; r < 4; ++r) {
        float e = exp2f(sacc[nf][r] - mnew);
        p[nf][r] = e;
        rs += e;
      }
    rs += __shfl_xor(rs, 16);
    rs += __shfl_xor(rs, 32);
    l_run = l_run * corr + rs;

    // broadcast corr into the O-accumulator row domain (row q = qw + lg*4 + r)
    float cq[4];
#pragma unroll
    for (int r = 0; r < 4; ++r) cq[r] = __shfl(corr, lg * 4 + r);
#pragma unroll
    for (int nf = 0; nf < 4; ++nf)
#pragma unroll
      for (int r = 0; r < 4; ++r) acc[nf][r] *= cq[r];

    // P -> LDS: lane owns q=lr, k = nf*16 + lg*4 + {0..3} -> one b64 per nf
#pragma unroll
    for (int nf = 0; nf < 4; ++nf) {
      uint2 w2;
      w2.x = (unsigned int)f2bf(p[nf][0]) | ((unsigned int)f2bf(p[nf][1]) << 16);
      w2.y = (unsigned int)f2bf(p[nf][2]) | ((unsigned int)f2bf(p[nf][3]) << 16);
      *(uint2*)&sP[w][lr * KLDT + nf * 16 + lg * 4] = w2;
    }

    // O += P V
#pragma unroll
    for (int kk = 0; kk < 2; ++kk) {
      short8 pf = *(const short8*)&sP[w][lr * KLDT + kk * 32 + lg * 8];
#pragma unroll
      for (int nf = 0; nf < 4; ++nf) {
        int d = nf * 16 + lr;
        int s0 = kk * 32 + lg * 8;
        short8 vf = *(const short8*)&sVt[d * KLDT + (s0 ^ ((d >> 3) << 3))];
        acc[nf] = __builtin_amdgcn_mfma_f32_16x16x32_bf16(pf, vf, acc[nf], 0, 0, 0);
      }
    }

    if (idx + 1 < nkv) {
      __syncthreads();
#pragma unroll
      for (int j = 0; j < 2; ++j) {
        int c = tid + j * 256, row = c >> 3, col8 = c & 7;
        *(uint4*)&sK[row * KLDT + col8 * 8] = rk[j];
        union { uint4 u4; u16t s[8]; } uv; uv.u4 = rv[j];
#pragma unroll
        for (int e = 0; e < 8; ++e) {
          int d = col8 * 8 + e;
          sVt[d * KLDT + (row ^ ((d >> 3) << 3))] = uv.s[e];
        }
      }
      __syncthreads();
    }
  }
#undef KVB

  if (windowed) {
    float lq[4];
#pragma unroll
    for (int r = 0; r < 4; ++r) lq[r] = __shfl(l_run, lg * 4 + r);
#pragma unroll
    for (int nf = 0; nf < 4; ++nf)
#pragma unroll
      for (int r = 0; r < 4; ++r) {
        float v = acc[nf][r] / lq[r];
        AO[(size_t)(qw + lg * 4 + r) * DMODEL + h * DKH + nf * 16 + lr] = f2bf(v);
      }
  } else {
    const int pbase = (h * NSPLIT + split) * 64;
#pragma unroll
    for (int nf = 0; nf < 4; ++nf)
#pragma unroll
      for (int r = 0; r < 4; ++r)
        pacc[(size_t)(pbase + w * 16 + lg * 4 + r) * 64 + nf * 16 + lr] = acc[nf][r];
    if (lane < 16) {
      int b = (pbase + w * 16 + lane) * 2;
      pml[b] = m_run;
      pml[b + 1] = l_run;
    }
  }
}

// ---------------- merge partials for global q rows (exp2 domain) ----------------
__global__ __launch_bounds__(256)
void merge_kernel(const float* __restrict__ pacc, const float* __restrict__ pml,
                  u16t* __restrict__ AO)
{
  const int h = blockIdx.x;
  const int tid = threadIdx.x;
  const int row = tid >> 2;
  const int d0 = (tid & 3) * 16;

  float M = -1e30f;
#pragma unroll
  for (int s = 0; s < NSPLIT; ++s)
    M = fmaxf(M, pml[((h * NSPLIT + s) * 64 + row) * 2]);

  float L = 0.f;
  float o[16];
#pragma unroll
  for (int e = 0; e < 16; ++e) o[e] = 0.f;

#pragma unroll
  for (int s = 0; s < NSPLIT; ++s) {
    int b = ((h * NSPLIT + s) * 64 + row) * 2;
    float sc = exp2f(pml[b] - M);
    L += pml[b + 1] * sc;
    const float4* a = (const float4*)(pacc + ((size_t)(h * NSPLIT + s) * 64 + row) * 64 + d0);
#pragma unroll
    for (int q4 = 0; q4 < 4; ++q4) {
      float4 av = a[q4];
      o[q4 * 4 + 0] += av.x * sc;
      o[q4 * 4 + 1] += av.y * sc;
      o[q4 * 4 + 2] += av.z * sc;
      o[q4 * 4 + 3] += av.w * sc;
    }
  }
  float inv = 1.f / L;
#pragma unroll
  for (int e = 0; e < 16; ++e)
    AO[(size_t)row * DMODEL + h * DKH + d0 + e] = f2bf(o[e] * inv);
}

// ---------------- launch ----------------
extern "C" void kernel_launch(void* const* d_in, const int* in_sizes, int n_in,
                              void* d_out, int out_size, void* d_ws, size_t ws_size,
                              hipStream_t stream) {
  const float* q   = (const float*)d_in[0];
  const float* k   = (const float*)d_in[1];
  const float* v   = (const float*)d_in[2];
  const float* w_q = (const float*)d_in[3];
  const float* b_q = (const float*)d_in[4];
  const float* w_k = (const float*)d_in[5];
  const float* b_k = (const float*)d_in[6];
  const float* w_v = (const float*)d_in[7];
  const float* b_v = (const float*)d_in[8];
  const float* w_o = (const float*)d_in[9];
  const float* b_o = (const float*)d_in[10];

  u16t* ws = (u16t*)d_ws;
  const size_t SZX = (size_t)S_LEN * DMODEL;   // 2^22
  const size_t SZW = (size_t)DMODEL * DMODEL;  // 2^20
  u16t* xq  = ws;
  u16t* xk  = xq + SZX;
  u16t* xv  = xk + SZX;
  u16t* wb0 = xv + SZX;
  u16t* wb1 = wb0 + SZW;
  u16t* wb2 = wb1 + SZW;
  u16t* wb3 = wb2 + SZW;
  u16t* Qp  = wb3 + SZW;
  u16t* Kp  = Qp + SZX;
  u16t* Vp  = Kp + SZX;
  u16t* AO  = xk;
  float* pacc = (float*)xq;
  float* pml  = pacc + (size_t)NHEADS * NSPLIT * 64 * 64;

  dim3 blk(256);

  cvt4_kernel<<<(int)(4 * SZW / 1024), blk, 0, stream>>>(w_q, w_k, w_v, w_o, wb0, wb1, wb2, wb3);
  cvt3_kernel<<<(int)(3 * SZX / 1024), blk, 0, stream>>>(q, k, v, xq, xk, xv);

  gemm_qkv<<<768, blk, 0, stream>>>(xq, xk, xv, wb0, wb1, wb2, b_q, b_k, b_v, Qp, Kp, Vp);

  attn_kernel<<<dim3(63 + NSPLIT, NHEADS), blk, 0, stream>>>(Qp, Kp, Vp, AO, pacc, pml);
  merge_kernel<<<NHEADS, blk, 0, stream>>>(pacc, pml, AO);

  gemm_o<<<512, blk, 0, stream>>>(AO, wb3, b_o, (float*)d_out);
}

// Round 8
// 122.153 us; speedup vs baseline: 4.0597x; 1.0613x over previous
//
#include <hip/hip_runtime.h>

#define S_LEN 4096
#define DMODEL 1024
#define NHEADS 16
#define DKH 64
#define WIN 256
#define GTOK 64
#define NSPLIT 8

typedef unsigned short u16t;
typedef __attribute__((ext_vector_type(8))) short short8;
typedef __attribute__((ext_vector_type(4))) float f32x4;

__device__ __forceinline__ u16t f2bf(float x) {
  union { float f; unsigned int u; } v; v.f = x;
  unsigned int r = v.u + 0x7FFFu + ((v.u >> 16) & 1u);
  return (u16t)(r >> 16);
}

__device__ __forceinline__ void gload_lds16(const u16t* g, u16t* l) {
  __builtin_amdgcn_global_load_lds(
      (const __attribute__((address_space(1))) void*)g,
      (__attribute__((address_space(3))) void*)l, 16, 0, 0);
}

// ---------------- fused fp32 -> bf16 converts ----------------
__global__ void cvt4_kernel(const float* __restrict__ s0, const float* __restrict__ s1,
                            const float* __restrict__ s2, const float* __restrict__ s3,
                            u16t* __restrict__ d0, u16t* __restrict__ d1,
                            u16t* __restrict__ d2, u16t* __restrict__ d3) {
  size_t i = (size_t)blockIdx.x * 1024 + threadIdx.x * 4;
  int which = (int)(i >> 20);
  size_t local = i & ((1u << 20) - 1);
  const float* s = which == 0 ? s0 : which == 1 ? s1 : which == 2 ? s2 : s3;
  u16t* d = which == 0 ? d0 : which == 1 ? d1 : which == 2 ? d2 : d3;
  float4 f = *(const float4*)(s + local);
  unsigned int lo = (unsigned int)f2bf(f.x) | ((unsigned int)f2bf(f.y) << 16);
  unsigned int hi = (unsigned int)f2bf(f.z) | ((unsigned int)f2bf(f.w) << 16);
  *(uint2*)(d + local) = make_uint2(lo, hi);
}

__global__ void cvt3_kernel(const float* __restrict__ s0, const float* __restrict__ s1,
                            const float* __restrict__ s2,
                            u16t* __restrict__ d0, u16t* __restrict__ d1,
                            u16t* __restrict__ d2) {
  size_t i = (size_t)blockIdx.x * 1024 + threadIdx.x * 4;
  int which = (int)(i >> 22);
  size_t local = i & ((1u << 22) - 1);
  const float* s = which == 0 ? s0 : which == 1 ? s1 : s2;
  u16t* d = which == 0 ? d0 : which == 1 ? d1 : d2;
  float4 f = *(const float4*)(s + local);
  unsigned int lo = (unsigned int)f2bf(f.x) | ((unsigned int)f2bf(f.y) << 16);
  unsigned int hi = (unsigned int)f2bf(f.z) | ((unsigned int)f2bf(f.w) << 16);
  *(uint2*)(d + local) = make_uint2(lo, hi);
}

// ---------------- bf16 GEMM body (m97 structure): Y = A @ B^T + bias, * alpha ----
#define BN 128
#define GBK 64

template<int OUT_F32, int BMT, int BIAS_ROW>
__device__ __forceinline__
void gemm_body(const u16t* __restrict__ A, const u16t* __restrict__ B,
               const float* __restrict__ bias, void* __restrict__ Y,
               int N, int K, float alpha, int m0, int n0)
{
  constexpr int MF = BMT / 32;
  constexpr int CA_ISS = BMT * 2 / 64;

  __shared__ __align__(16) u16t sA[BMT * GBK];
  __shared__ __align__(16) u16t sB[BN * GBK];

  const int tid = threadIdx.x;
  const int lane = tid & 63;
  const int lr = lane & 15, lg = lane >> 4;
  const int w = tid >> 6;
  const int wm = (w >> 1) * (MF * 16), wn = (w & 1) * 64;

  f32x4 acc[MF][4] = {};
  const int nk = K / GBK;

  for (int kt = 0; kt < nk; ++kt) {
    if (kt) __syncthreads();
#pragma unroll
    for (int i = 0; i < CA_ISS; ++i) {
      int c0 = w * (BMT * 2) + i * 64;
      int c = c0 + lane;
      int row = c >> 3, g = (c & 7) ^ (row & 7);
      gload_lds16(A + (size_t)(m0 + row) * K + kt * GBK + g * 8, sA + (size_t)c0 * 8);
    }
#pragma unroll
    for (int i = 0; i < 4; ++i) {
      int c0 = w * 256 + i * 64;
      int c = c0 + lane;
      int row = c >> 3, g = (c & 7) ^ (row & 7);
      gload_lds16(B + (size_t)(n0 + row) * K + kt * GBK + g * 8, sB + (size_t)c0 * 8);
    }
    __syncthreads();

    short8 af[MF][2], bf[4][2];
#pragma unroll
    for (int mf = 0; mf < MF; ++mf)
#pragma unroll
      for (int kk = 0; kk < 2; ++kk) {
        int s = ((kk * 4 + lg) ^ (lr & 7));
        af[mf][kk] = *(const short8*)&sA[(wm + mf * 16 + lr) * GBK + s * 8];
      }
#pragma unroll
    for (int nf = 0; nf < 4; ++nf)
#pragma unroll
      for (int kk = 0; kk < 2; ++kk) {
        int s = ((kk * 4 + lg) ^ (lr & 7));
        bf[nf][kk] = *(const short8*)&sB[(wn + nf * 16 + lr) * GBK + s * 8];
      }
#pragma unroll
    for (int kk = 0; kk < 2; ++kk)
#pragma unroll
      for (int mf = 0; mf < MF; ++mf)
#pragma unroll
        for (int nf = 0; nf < 4; ++nf)
          acc[mf][nf] = __builtin_amdgcn_mfma_f32_16x16x32_bf16(af[mf][kk], bf[nf][kk], acc[mf][nf], 0, 0, 0);
  }

#pragma unroll
  for (int nf = 0; nf < 4; ++nf) {
    int col = n0 + wn + nf * 16 + lr;
    float bvc = BIAS_ROW ? 0.f : bias[col];
#pragma unroll
    for (int mf = 0; mf < MF; ++mf)
#pragma unroll
      for (int r = 0; r < 4; ++r) {
        int row = m0 + wm + mf * 16 + lg * 4 + r;
        float bv = BIAS_ROW ? bias[row] : bvc;
        float v = (acc[mf][nf][r] + bv) * alpha;
        if (OUT_F32) ((float*)Y)[(size_t)row * N + col] = v;
        else         ((u16t*)Y)[(size_t)row * N + col] = f2bf(v);
      }
  }
}

// fused Q/K/V projection: 768 blocks (1D), bijective XCD swizzle (96 blocks/XCD)
// Q scaled by 1/sqrt(dk)*log2(e); V produced TRANSPOSED (V^T = Wv @ X^T).
#define QSCALE 0.18033688011112042f
__global__ __launch_bounds__(256)
void gemm_qkv(const u16t* __restrict__ xq, const u16t* __restrict__ xk, const u16t* __restrict__ xv,
              const u16t* __restrict__ wq, const u16t* __restrict__ wk, const u16t* __restrict__ wv,
              const float* __restrict__ bq, const float* __restrict__ bk, const float* __restrict__ bv,
              u16t* __restrict__ Qp, u16t* __restrict__ Kp, u16t* __restrict__ Vt)
{
  int b = blockIdx.x;
  int wid = (b & 7) * 96 + (b >> 3);
  int z = wid >> 8;
  int rem = wid & 255;
  if (z == 0) {
    gemm_body<0, 128, 0>(xq, wq, bq, Qp, DMODEL, DMODEL, QSCALE, (rem >> 3) * 128, (rem & 7) * BN);
  } else if (z == 1) {
    gemm_body<0, 128, 0>(xk, wk, bk, Kp, DMODEL, DMODEL, 1.0f, (rem >> 3) * 128, (rem & 7) * BN);
  } else {
    // V^T[i][s] = dot(wv_i, xv_s) + bv[i];  M=1024 (8 m-blocks), N=4096 (32 n-blocks)
    gemm_body<0, 128, 1>(wv, xv, bv, Vt, S_LEN, DMODEL, 1.0f, (rem & 7) * 128, (rem >> 3) * BN);
  }
}

__global__ __launch_bounds__(256)
void gemm_o(const u16t* __restrict__ A, const u16t* __restrict__ B,
            const float* __restrict__ bias, float* __restrict__ Y)
{
  int b = blockIdx.x;
  int wid = (b & 7) * 64 + (b >> 3);
  int my = wid >> 3, mx = wid & 7;
  gemm_body<1, 64, 0>(A, B, bias, Y, DMODEL, DMODEL, 1.0f, my * 64, mx * BN);
}

// ---------------- flash-style sparse attention (swapped QK^T, gload_lds dbuf) ----
#define KLDT 72  // sP row stride in u16

__global__ __launch_bounds__(256)
void attn_kernel(const u16t* __restrict__ Qp, const u16t* __restrict__ Kp,
                 const u16t* __restrict__ Vt, u16t* __restrict__ AO,
                 float* __restrict__ pacc, float* __restrict__ pml)
{
  __shared__ __align__(16) u16t sK[2][64 * 64];
  __shared__ __align__(16) u16t sV[2][64 * 64];
  __shared__ __align__(16) u16t sP[4][16 * KLDT];

  const int h = blockIdx.y;
  const int tid = threadIdx.x, w = tid >> 6, lane = tid & 63;
  const int lr = lane & 15, lg = lane >> 4;

  const bool windowed = (blockIdx.x < 63);
  const int qb = windowed ? (blockIdx.x + 1) : 0;
  const int split = windowed ? 0 : (blockIdx.x - 63);
  const int qw = qb * 64 + w * 16;

  short8 qf[2];
#pragma unroll
  for (int kk = 0; kk < 2; ++kk)
    qf[kk] = *(const short8*)(Qp + (size_t)(qw + lr) * DMODEL + h * DKH + kk * 32 + lg * 8);

  f32x4 acc[4] = {};
  float m_run = -1e30f, l_run = 0.f;  // per-lane: this lane's q row is qw+lr

  int lo = 1, nkv;
  if (windowed) {
    lo = (qb - 4 < 1) ? 1 : qb - 4;
    int hi = (qb + 4 > 63) ? 63 : qb + 4;
    nkv = hi - lo + 2;  // {0} ∪ [lo..hi]
  } else {
    nkv = 64 / NSPLIT;
  }

#define KVB(idx) (windowed ? ((idx) == 0 ? 0 : lo + (idx) - 1) : (split * (64 / NSPLIT) + (idx)))

  // stage tile kvb into buffer buf: K rows=k, V^T rows=d; pre-swizzled source cols
  auto stage = [&](int buf, int kvb) {
    int kv0 = kvb * 64;
#pragma unroll
    for (int j = 0; j < 2; ++j) {
      int c = tid + j * 256;
      int row = c >> 3, g = (c & 7) ^ (row & 7);
      gload_lds16(Kp + (size_t)(kv0 + row) * DMODEL + h * DKH + g * 8, &sK[buf][c * 8]);
    }
#pragma unroll
    for (int j = 0; j < 2; ++j) {
      int c = tid + j * 256;
      int row = c >> 3, g = (c & 7) ^ (row & 7);
      gload_lds16(Vt + (size_t)(h * DKH + row) * S_LEN + kv0 + g * 8, &sV[buf][c * 8]);
    }
  };

  stage(0, KVB(0));
  __syncthreads();

  for (int idx = 0; idx < nkv; ++idx) {
    const int buf = idx & 1;
    const int kvb = KVB(idx);
    const int kv0 = kvb * 64;

    if (idx + 1 < nkv) stage(buf ^ 1, KVB(idx + 1));

    // S^T = K Q^T: sacc[nf][r] = S[k = kv0 + nf*16 + lg*4 + r][q = qw + lr]
    f32x4 sacc[4] = {};
#pragma unroll
    for (int kk = 0; kk < 2; ++kk)
#pragma unroll
      for (int nf = 0; nf < 4; ++nf) {
        int s = ((kk * 4 + lg) ^ (lr & 7));
        short8 kf = *(const short8*)&sK[buf][(nf * 16 + lr) * 64 + s * 8];
        sacc[nf] = __builtin_amdgcn_mfma_f32_16x16x32_bf16(kf, qf[kk], sacc[nf], 0, 0, 0);
      }

    // mask: only the two edge tiles can mask, and NEVER the global tile kvb==0
    if (windowed && (kvb == qb + 4 || (kvb == qb - 4 && kvb > 0))) {
      int qg = qw + lr;
#pragma unroll
      for (int nf = 0; nf < 4; ++nf)
#pragma unroll
        for (int r = 0; r < 4; ++r) {
          int sg = kv0 + nf * 16 + lg * 4 + r;
          int diff = qg - sg; if (diff < 0) diff = -diff;
          if (diff > WIN) sacc[nf][r] = -1e30f;
        }
    }

    // online softmax, exp2 domain; lane owns q = qw+lr (reduce over lg groups)
    float rm = sacc[0][0];
#pragma unroll
    for (int nf = 0; nf < 4; ++nf)
#pragma unroll
      for (int r = 0; r < 4; ++r)
        rm = fmaxf(rm, sacc[nf][r]);
    rm = fmaxf(rm, __shfl_xor(rm, 16));
    rm = fmaxf(rm, __shfl_xor(rm, 32));

    // defer-max (T13): skip rescale unless max jumped by > ~8 nats (11 bits)
    if (!__all(rm <= m_run + 11.0f)) {
      float mnew = fmaxf(m_run, rm);
      float corr = exp2f(m_run - mnew);
      m_run = mnew;
      l_run *= corr;
      float cq[4];
#pragma unroll
      for (int r = 0; r < 4; ++r) cq[r] = __shfl(corr, lg * 4 + r);
#pragma unroll
      for (int nf = 0; nf < 4; ++nf)
#pragma unroll
        for (int r = 0; r < 4; ++r) acc[nf][r] *= cq[r];
    }

    float p[4][4];
    float rs = 0.f;
#pragma unroll
    for (int nf = 0; nf < 4; ++nf)
#pragma unroll
      for (int r = 0; r < 4; ++r) {
        float e = exp2f(sacc[nf][r] - m_run);
        p[nf][r] = e;
        rs += e;
      }
    rs += __shfl_xor(rs, 16);
    rs += __shfl_xor(rs, 32);
    l_run += rs;

    // P -> LDS: lane owns q=lr, k = nf*16 + lg*4 + {0..3} -> one b64 per nf
#pragma unroll
    for (int nf = 0; nf < 4; ++nf) {
      uint2 w2;
      w2.x = (unsigned int)f2bf(p[nf][0]) | ((unsigned int)f2bf(p[nf][1]) << 16);
      w2.y = (unsigned int)f2bf(p[nf][2]) | ((unsigned int)f2bf(p[nf][3]) << 16);
      *(uint2*)&sP[w][lr * KLDT + nf * 16 + lg * 4] = w2;
    }

    // O += P V : vf = V^T row d = nf*16+lr, k-cols kk*32+lg*8 (same swizzle as K)
#pragma unroll
    for (int kk = 0; kk < 2; ++kk) {
      short8 pf = *(const short8*)&sP[w][lr * KLDT + kk * 32 + lg * 8];
#pragma unroll
      for (int nf = 0; nf < 4; ++nf) {
        int s = ((kk * 4 + lg) ^ (lr & 7));
        short8 vf = *(const short8*)&sV[buf][(nf * 16 + lr) * 64 + s * 8];
        acc[nf] = __builtin_amdgcn_mfma_f32_16x16x32_bf16(pf, vf, acc[nf], 0, 0, 0);
      }
    }

    if (idx + 1 < nkv) __syncthreads();  // drains next-tile gloads + joins waves
  }
#undef KVB

  if (windowed) {
    float lq[4];
#pragma unroll
    for (int r = 0; r < 4; ++r) lq[r] = __shfl(l_run, lg * 4 + r);
#pragma unroll
    for (int nf = 0; nf < 4; ++nf)
#pragma unroll
      for (int r = 0; r < 4; ++r) {
        float v = acc[nf][r] / lq[r];
        AO[(size_t)(qw + lg * 4 + r) * DMODEL + h * DKH + nf * 16 + lr] = f2bf(v);
      }
  } else {
    const int pbase = (h * NSPLIT + split) * 64;
#pragma unroll
    for (int nf = 0; nf < 4; ++nf)
#pragma unroll
      for (int r = 0; r < 4; ++r)
        pacc[(size_t)(pbase + w * 16 + lg * 4 + r) * 64 + nf * 16 + lr] = acc[nf][r];
    if (lane < 16) {
      int b = (pbase + w * 16 + lane) * 2;
      pml[b] = m_run;
      pml[b + 1] = l_run;
    }
  }
}

// ---------------- merge partials for global q rows (exp2 domain) ----------------
__global__ __launch_bounds__(256)
void merge_kernel(const float* __restrict__ pacc, const float* __restrict__ pml,
                  u16t* __restrict__ AO)
{
  const int h = blockIdx.x;
  const int tid = threadIdx.x;
  const int row = tid >> 2;
  const int d0 = (tid & 3) * 16;

  float M = -1e30f;
#pragma unroll
  for (int s = 0; s < NSPLIT; ++s)
    M = fmaxf(M, pml[((h * NSPLIT + s) * 64 + row) * 2]);

  float L = 0.f;
  float o[16];
#pragma unroll
  for (int e = 0; e < 16; ++e) o[e] = 0.f;

#pragma unroll
  for (int s = 0; s < NSPLIT; ++s) {
    int b = ((h * NSPLIT + s) * 64 + row) * 2;
    float sc = exp2f(pml[b] - M);
    L += pml[b + 1] * sc;
    const float4* a = (const float4*)(pacc + ((size_t)(h * NSPLIT + s) * 64 + row) * 64 + d0);
#pragma unroll
    for (int q4 = 0; q4 < 4; ++q4) {
      float4 av = a[q4];
      o[q4 * 4 + 0] += av.x * sc;
      o[q4 * 4 + 1] += av.y * sc;
      o[q4 * 4 + 2] += av.z * sc;
      o[q4 * 4 + 3] += av.w * sc;
    }
  }
  float inv = 1.f / L;
#pragma unroll
  for (int e = 0; e < 16; ++e)
    AO[(size_t)row * DMODEL + h * DKH + d0 + e] = f2bf(o[e] * inv);
}

// ---------------- launch ----------------
extern "C" void kernel_launch(void* const* d_in, const int* in_sizes, int n_in,
                              void* d_out, int out_size, void* d_ws, size_t ws_size,
                              hipStream_t stream) {
  const float* q   = (const float*)d_in[0];
  const float* k   = (const float*)d_in[1];
  const float* v   = (const float*)d_in[2];
  const float* w_q = (const float*)d_in[3];
  const float* b_q = (const float*)d_in[4];
  const float* w_k = (const float*)d_in[5];
  const float* b_k = (const float*)d_in[6];
  const float* w_v = (const float*)d_in[7];
  const float* b_v = (const float*)d_in[8];
  const float* w_o = (const float*)d_in[9];
  const float* b_o = (const float*)d_in[10];

  u16t* ws = (u16t*)d_ws;
  const size_t SZX = (size_t)S_LEN * DMODEL;   // 2^22
  const size_t SZW = (size_t)DMODEL * DMODEL;  // 2^20
  u16t* xq  = ws;
  u16t* xk  = xq + SZX;
  u16t* xv  = xk + SZX;
  u16t* wb0 = xv + SZX;
  u16t* wb1 = wb0 + SZW;
  u16t* wb2 = wb1 + SZW;
  u16t* wb3 = wb2 + SZW;
  u16t* Qp  = wb3 + SZW;
  u16t* Kp  = Qp + SZX;
  u16t* Vt  = Kp + SZX;   // V^T: [NHEADS*DKH][S_LEN]
  u16t* AO  = xk;         // dead after gemm_qkv
  float* pacc = (float*)xq;
  float* pml  = pacc + (size_t)NHEADS * NSPLIT * 64 * 64;

  dim3 blk(256);

  cvt4_kernel<<<(int)(4 * SZW / 1024), blk, 0, stream>>>(w_q, w_k, w_v, w_o, wb0, wb1, wb2, wb3);
  cvt3_kernel<<<(int)(3 * SZX / 1024), blk, 0, stream>>>(q, k, v, xq, xk, xv);

  gemm_qkv<<<768, blk, 0, stream>>>(xq, xk, xv, wb0, wb1, wb2, b_q, b_k, b_v, Qp, Kp, Vt);

  attn_kernel<<<dim3(63 + NSPLIT, NHEADS), blk, 0, stream>>>(Qp, Kp, Vt, AO, pacc, pml);
  merge_kernel<<<NHEADS, blk, 0, stream>>>(pacc, pml, AO);

  gemm_o<<<512, blk, 0, stream>>>(AO, wb3, b_o, (float*)d_out);
}

// Round 9
// 117.744 us; speedup vs baseline: 4.2117x; 1.0374x over previous
//
#include <hip/hip_runtime.h>

#define S_LEN 4096
#define DMODEL 1024
#define NHEADS 16
#define DKH 64
#define WIN 256
#define GTOK 64
#define NSPLIT 8

typedef unsigned short u16t;
typedef __attribute__((ext_vector_type(8))) short short8;
typedef __attribute__((ext_vector_type(4))) float f32x4;

__device__ __forceinline__ u16t f2bf(float x) {
  union { float f; unsigned int u; } v; v.f = x;
  unsigned int r = v.u + 0x7FFFu + ((v.u >> 16) & 1u);
  return (u16t)(r >> 16);
}

__device__ __forceinline__ unsigned int cvtpk(float lo, float hi) {
  unsigned int r;
  asm("v_cvt_pk_bf16_f32 %0, %1, %2" : "=v"(r) : "v"(lo), "v"(hi));
  return r;
}

__device__ __forceinline__ void gload_lds16(const u16t* g, u16t* l) {
  __builtin_amdgcn_global_load_lds(
      (const __attribute__((address_space(1))) void*)g,
      (__attribute__((address_space(3))) void*)l, 16, 0, 0);
}

// ---------------- fused fp32 -> bf16 convert (all 7 tensors, one launch) -------
__global__ void cvt_all(const float* __restrict__ s0, const float* __restrict__ s1,
                        const float* __restrict__ s2, const float* __restrict__ s3,
                        const float* __restrict__ s4, const float* __restrict__ s5,
                        const float* __restrict__ s6,
                        u16t* __restrict__ d0, u16t* __restrict__ d1,
                        u16t* __restrict__ d2, u16t* __restrict__ d3,
                        u16t* __restrict__ d4, u16t* __restrict__ d5,
                        u16t* __restrict__ d6) {
  size_t i = (size_t)blockIdx.x * 1024 + threadIdx.x * 4;
  const float* s; u16t* d; size_t local;
  if (i < ((size_t)4 << 20)) {          // 4 weight matrices, 2^20 each
    int which = (int)(i >> 20);
    local = i & ((1u << 20) - 1);
    s = which == 0 ? s0 : which == 1 ? s1 : which == 2 ? s2 : s3;
    d = which == 0 ? d0 : which == 1 ? d1 : which == 2 ? d2 : d3;
  } else {                              // 3 activations, 2^22 each
    size_t j = i - ((size_t)4 << 20);
    int which = (int)(j >> 22);
    local = j & ((1u << 22) - 1);
    s = which == 0 ? s4 : which == 1 ? s5 : s6;
    d = which == 0 ? d4 : which == 1 ? d5 : d6;
  }
  float4 f = *(const float4*)(s + local);
  unsigned int lo = (unsigned int)f2bf(f.x) | ((unsigned int)f2bf(f.y) << 16);
  unsigned int hi = (unsigned int)f2bf(f.z) | ((unsigned int)f2bf(f.w) << 16);
  *(uint2*)(d + local) = make_uint2(lo, hi);
}

// ---------------- bf16 GEMM body (m97 structure): Y = A @ B^T + bias, * alpha ----
#define BN 128
#define GBK 64

template<int OUT_F32, int BMT, int BIAS_ROW>
__device__ __forceinline__
void gemm_body(const u16t* __restrict__ A, const u16t* __restrict__ B,
               const float* __restrict__ bias, void* __restrict__ Y,
               int N, int K, float alpha, int m0, int n0)
{
  constexpr int MF = BMT / 32;
  constexpr int CA_ISS = BMT * 2 / 64;

  __shared__ __align__(16) u16t sA[BMT * GBK];
  __shared__ __align__(16) u16t sB[BN * GBK];

  const int tid = threadIdx.x;
  const int lane = tid & 63;
  const int lr = lane & 15, lg = lane >> 4;
  const int w = tid >> 6;
  const int wm = (w >> 1) * (MF * 16), wn = (w & 1) * 64;

  f32x4 acc[MF][4] = {};
  const int nk = K / GBK;

  for (int kt = 0; kt < nk; ++kt) {
    if (kt) __syncthreads();
#pragma unroll
    for (int i = 0; i < CA_ISS; ++i) {
      int c0 = w * (BMT * 2) + i * 64;
      int c = c0 + lane;
      int row = c >> 3, g = (c & 7) ^ (row & 7);
      gload_lds16(A + (size_t)(m0 + row) * K + kt * GBK + g * 8, sA + (size_t)c0 * 8);
    }
#pragma unroll
    for (int i = 0; i < 4; ++i) {
      int c0 = w * 256 + i * 64;
      int c = c0 + lane;
      int row = c >> 3, g = (c & 7) ^ (row & 7);
      gload_lds16(B + (size_t)(n0 + row) * K + kt * GBK + g * 8, sB + (size_t)c0 * 8);
    }
    __syncthreads();

    short8 af[MF][2], bf[4][2];
#pragma unroll
    for (int mf = 0; mf < MF; ++mf)
#pragma unroll
      for (int kk = 0; kk < 2; ++kk) {
        int s = ((kk * 4 + lg) ^ (lr & 7));
        af[mf][kk] = *(const short8*)&sA[(wm + mf * 16 + lr) * GBK + s * 8];
      }
#pragma unroll
    for (int nf = 0; nf < 4; ++nf)
#pragma unroll
      for (int kk = 0; kk < 2; ++kk) {
        int s = ((kk * 4 + lg) ^ (lr & 7));
        bf[nf][kk] = *(const short8*)&sB[(wn + nf * 16 + lr) * GBK + s * 8];
      }
    __builtin_amdgcn_s_setprio(1);
#pragma unroll
    for (int kk = 0; kk < 2; ++kk)
#pragma unroll
      for (int mf = 0; mf < MF; ++mf)
#pragma unroll
        for (int nf = 0; nf < 4; ++nf)
          acc[mf][nf] = __builtin_amdgcn_mfma_f32_16x16x32_bf16(af[mf][kk], bf[nf][kk], acc[mf][nf], 0, 0, 0);
    __builtin_amdgcn_s_setprio(0);
  }

#pragma unroll
  for (int nf = 0; nf < 4; ++nf) {
    int col = n0 + wn + nf * 16 + lr;
    float bvc = BIAS_ROW ? 0.f : bias[col];
#pragma unroll
    for (int mf = 0; mf < MF; ++mf)
#pragma unroll
      for (int r = 0; r < 4; ++r) {
        int row = m0 + wm + mf * 16 + lg * 4 + r;
        float bv = BIAS_ROW ? bias[row] : bvc;
        float v = (acc[mf][nf][r] + bv) * alpha;
        if (OUT_F32) ((float*)Y)[(size_t)row * N + col] = v;
        else         ((u16t*)Y)[(size_t)row * N + col] = f2bf(v);
      }
  }
}

// fused Q/K/V projection: 768 blocks (1D), bijective XCD swizzle (96 blocks/XCD)
// Q scaled by 1/sqrt(dk)*log2(e); V produced TRANSPOSED (V^T = Wv @ X^T).
#define QSCALE 0.18033688011112042f
__global__ __launch_bounds__(256)
void gemm_qkv(const u16t* __restrict__ xq, const u16t* __restrict__ xk, const u16t* __restrict__ xv,
              const u16t* __restrict__ wq, const u16t* __restrict__ wk, const u16t* __restrict__ wv,
              const float* __restrict__ bq, const float* __restrict__ bk, const float* __restrict__ bv,
              u16t* __restrict__ Qp, u16t* __restrict__ Kp, u16t* __restrict__ Vt)
{
  int b = blockIdx.x;
  int wid = (b & 7) * 96 + (b >> 3);
  int z = wid >> 8;
  int rem = wid & 255;
  if (z == 0) {
    gemm_body<0, 128, 0>(xq, wq, bq, Qp, DMODEL, DMODEL, QSCALE, (rem >> 3) * 128, (rem & 7) * BN);
  } else if (z == 1) {
    gemm_body<0, 128, 0>(xk, wk, bk, Kp, DMODEL, DMODEL, 1.0f, (rem >> 3) * 128, (rem & 7) * BN);
  } else {
    gemm_body<0, 128, 1>(wv, xv, bv, Vt, S_LEN, DMODEL, 1.0f, (rem & 7) * 128, (rem >> 3) * BN);
  }
}

__global__ __launch_bounds__(256)
void gemm_o(const u16t* __restrict__ A, const u16t* __restrict__ B,
            const float* __restrict__ bias, float* __restrict__ Y)
{
  int b = blockIdx.x;
  int wid = (b & 7) * 64 + (b >> 3);
  int my = wid >> 3, mx = wid & 7;
  gemm_body<1, 64, 0>(A, B, bias, Y, DMODEL, DMODEL, 1.0f, my * 64, mx * BN);
}

// ---------------- flash-style sparse attention (swapped QK^T, gload_lds dbuf) ----
__global__ __launch_bounds__(256)
void attn_kernel(const u16t* __restrict__ Qp, const u16t* __restrict__ Kp,
                 const u16t* __restrict__ Vt, u16t* __restrict__ AO,
                 float* __restrict__ pacc, float* __restrict__ pml)
{
  // 16 + 16 + 8 = 40 KB exactly -> 4 blocks/CU
  __shared__ __align__(16) u16t sK[2][64 * 64];
  __shared__ __align__(16) u16t sV[2][64 * 64];
  __shared__ __align__(16) u16t sP[4][16 * 64];

  const int h = blockIdx.y;
  const int tid = threadIdx.x, w = tid >> 6, lane = tid & 63;
  const int lr = lane & 15, lg = lane >> 4;

  const bool windowed = (blockIdx.x < 63);
  const int qb = windowed ? (blockIdx.x + 1) : 0;
  const int split = windowed ? 0 : (blockIdx.x - 63);
  const int qw = qb * 64 + w * 16;

  short8 qf[2];
#pragma unroll
  for (int kk = 0; kk < 2; ++kk)
    qf[kk] = *(const short8*)(Qp + (size_t)(qw + lr) * DMODEL + h * DKH + kk * 32 + lg * 8);

  f32x4 acc[4] = {};
  float m_run = -1e30f, l_run = 0.f;  // per-lane: this lane's q row is qw+lr

  int lo = 1, nkv;
  if (windowed) {
    lo = (qb - 4 < 1) ? 1 : qb - 4;
    int hi = (qb + 4 > 63) ? 63 : qb + 4;
    nkv = hi - lo + 2;  // {0} ∪ [lo..hi]
  } else {
    nkv = 64 / NSPLIT;
  }

#define KVB(idx) (windowed ? ((idx) == 0 ? 0 : lo + (idx) - 1) : (split * (64 / NSPLIT) + (idx)))

  auto stage = [&](int buf, int kvb) {
    int kv0 = kvb * 64;
#pragma unroll
    for (int j = 0; j < 2; ++j) {
      int c = tid + j * 256;
      int row = c >> 3, g = (c & 7) ^ (row & 7);
      gload_lds16(Kp + (size_t)(kv0 + row) * DMODEL + h * DKH + g * 8, &sK[buf][c * 8]);
    }
#pragma unroll
    for (int j = 0; j < 2; ++j) {
      int c = tid + j * 256;
      int row = c >> 3, g = (c & 7) ^ (row & 7);
      gload_lds16(Vt + (size_t)(h * DKH + row) * S_LEN + kv0 + g * 8, &sV[buf][c * 8]);
    }
  };

  stage(0, KVB(0));
  __syncthreads();

  for (int idx = 0; idx < nkv; ++idx) {
    const int buf = idx & 1;
    const int kvb = KVB(idx);
    const int kv0 = kvb * 64;

    if (idx + 1 < nkv) stage(buf ^ 1, KVB(idx + 1));

    // S^T = K Q^T: sacc[nf][r] = S[k = kv0 + nf*16 + lg*4 + r][q = qw + lr]
    f32x4 sacc[4] = {};
    __builtin_amdgcn_s_setprio(1);
#pragma unroll
    for (int kk = 0; kk < 2; ++kk)
#pragma unroll
      for (int nf = 0; nf < 4; ++nf) {
        int s = ((kk * 4 + lg) ^ (lr & 7));
        short8 kf = *(const short8*)&sK[buf][(nf * 16 + lr) * 64 + s * 8];
        sacc[nf] = __builtin_amdgcn_mfma_f32_16x16x32_bf16(kf, qf[kk], sacc[nf], 0, 0, 0);
      }
    __builtin_amdgcn_s_setprio(0);

    // mask: only the two edge tiles can mask, and NEVER the global tile kvb==0
    if (windowed && (kvb == qb + 4 || (kvb == qb - 4 && kvb > 0))) {
      int qg = qw + lr;
#pragma unroll
      for (int nf = 0; nf < 4; ++nf)
#pragma unroll
        for (int r = 0; r < 4; ++r) {
          int sg = kv0 + nf * 16 + lg * 4 + r;
          int diff = qg - sg; if (diff < 0) diff = -diff;
          if (diff > WIN) sacc[nf][r] = -1e30f;
        }
    }

    // online softmax, exp2 domain; lane owns q = qw+lr (reduce over lg groups)
    // max via v_max3-friendly triples
    float rm0 = fmaxf(fmaxf(sacc[0][0], sacc[0][1]), sacc[0][2]);
    float rm1 = fmaxf(fmaxf(sacc[0][3], sacc[1][0]), sacc[1][1]);
    float rm2 = fmaxf(fmaxf(sacc[1][2], sacc[1][3]), sacc[2][0]);
    float rm3 = fmaxf(fmaxf(sacc[2][1], sacc[2][2]), sacc[2][3]);
    float rm4 = fmaxf(fmaxf(sacc[3][0], sacc[3][1]), sacc[3][2]);
    float rm = fmaxf(fmaxf(rm0, rm1), fmaxf(fmaxf(rm2, rm3), fmaxf(rm4, sacc[3][3])));
    rm = fmaxf(rm, __shfl_xor(rm, 16));
    rm = fmaxf(rm, __shfl_xor(rm, 32));

    // defer-max (T13): skip rescale unless max jumped by > 11 bits (~8 nats)
    if (!__all(rm <= m_run + 11.0f)) {
      float mnew = fmaxf(m_run, rm);
      float corr = exp2f(m_run - mnew);
      m_run = mnew;
      l_run *= corr;
      float cq[4];
#pragma unroll
      for (int r = 0; r < 4; ++r) cq[r] = __shfl(corr, lg * 4 + r);
#pragma unroll
      for (int nf = 0; nf < 4; ++nf)
#pragma unroll
        for (int r = 0; r < 4; ++r) acc[nf][r] *= cq[r];
    }

    float p[4][4];
    float rs = 0.f;
#pragma unroll
    for (int nf = 0; nf < 4; ++nf)
#pragma unroll
      for (int r = 0; r < 4; ++r) {
        float e = exp2f(sacc[nf][r] - m_run);
        p[nf][r] = e;
        rs += e;
      }
    rs += __shfl_xor(rs, 16);
    rs += __shfl_xor(rs, 32);
    l_run += rs;

    // P -> LDS via v_cvt_pk_bf16_f32; stride 64 with XOR-block swizzle
    // write block b = nf*2+(lg>>1) holds k in [8b, 8b+8); b ^= lr&7 both sides
#pragma unroll
    for (int nf = 0; nf < 4; ++nf) {
      unsigned int lo32 = cvtpk(p[nf][0], p[nf][1]);
      unsigned int hi32 = cvtpk(p[nf][2], p[nf][3]);
      int blk = (nf * 2 + (lg >> 1)) ^ (lr & 7);
      *(uint2*)&sP[w][lr * 64 + blk * 8 + (lg & 1) * 4] = make_uint2(lo32, hi32);
    }

    // O += P V : pf reads block kk*4+lg (same XOR); vf = V^T row d = nf*16+lr
#pragma unroll
    for (int kk = 0; kk < 2; ++kk) {
      short8 pf = *(const short8*)&sP[w][lr * 64 + (((kk * 4 + lg) ^ (lr & 7))) * 8];
      __builtin_amdgcn_s_setprio(1);
#pragma unroll
      for (int nf = 0; nf < 4; ++nf) {
        int s = ((kk * 4 + lg) ^ (lr & 7));
        short8 vf = *(const short8*)&sV[buf][(nf * 16 + lr) * 64 + s * 8];
        acc[nf] = __builtin_amdgcn_mfma_f32_16x16x32_bf16(pf, vf, acc[nf], 0, 0, 0);
      }
      __builtin_amdgcn_s_setprio(0);
    }

    if (idx + 1 < nkv) __syncthreads();  // drains next-tile gloads + joins waves
  }
#undef KVB

  if (windowed) {
    float lq[4];
#pragma unroll
    for (int r = 0; r < 4; ++r) lq[r] = __shfl(l_run, lg * 4 + r);
#pragma unroll
    for (int nf = 0; nf < 4; ++nf)
#pragma unroll
      for (int r = 0; r < 4; ++r) {
        float v = acc[nf][r] / lq[r];
        AO[(size_t)(qw + lg * 4 + r) * DMODEL + h * DKH + nf * 16 + lr] = f2bf(v);
      }
  } else {
    const int pbase = (h * NSPLIT + split) * 64;
#pragma unroll
    for (int nf = 0; nf < 4; ++nf)
#pragma unroll
      for (int r = 0; r < 4; ++r)
        pacc[(size_t)(pbase + w * 16 + lg * 4 + r) * 64 + nf * 16 + lr] = acc[nf][r];
    if (lane < 16) {
      int b = (pbase + w * 16 + lane) * 2;
      pml[b] = m_run;
      pml[b + 1] = l_run;
    }
  }
}

// ---------------- merge partials for global q rows (exp2 domain) ----------------
__global__ __launch_bounds__(256)
void merge_kernel(const float* __restrict__ pacc, const float* __restrict__ pml,
                  u16t* __restrict__ AO)
{
  const int h = blockIdx.x;
  const int tid = threadIdx.x;
  const int row = tid >> 2;
  const int d0 = (tid & 3) * 16;

  float M = -1e30f;
#pragma unroll
  for (int s = 0; s < NSPLIT; ++s)
    M = fmaxf(M, pml[((h * NSPLIT + s) * 64 + row) * 2]);

  float L = 0.f;
  float o[16];
#pragma unroll
  for (int e = 0; e < 16; ++e) o[e] = 0.f;

#pragma unroll
  for (int s = 0; s < NSPLIT; ++s) {
    int b = ((h * NSPLIT + s) * 64 + row) * 2;
    float sc = exp2f(pml[b] - M);
    L += pml[b + 1] * sc;
    const float4* a = (const float4*)(pacc + ((size_t)(h * NSPLIT + s) * 64 + row) * 64 + d0);
#pragma unroll
    for (int q4 = 0; q4 < 4; ++q4) {
      float4 av = a[q4];
      o[q4 * 4 + 0] += av.x * sc;
      o[q4 * 4 + 1] += av.y * sc;
      o[q4 * 4 + 2] += av.z * sc;
      o[q4 * 4 + 3] += av.w * sc;
    }
  }
  float inv = 1.f / L;
#pragma unroll
  for (int e = 0; e < 16; ++e)
    AO[(size_t)row * DMODEL + h * DKH + d0 + e] = f2bf(o[e] * inv);
}

// ---------------- launch ----------------
extern "C" void kernel_launch(void* const* d_in, const int* in_sizes, int n_in,
                              void* d_out, int out_size, void* d_ws, size_t ws_size,
                              hipStream_t stream) {
  const float* q   = (const float*)d_in[0];
  const float* k   = (const float*)d_in[1];
  const float* v   = (const float*)d_in[2];
  const float* w_q = (const float*)d_in[3];
  const float* b_q = (const float*)d_in[4];
  const float* w_k = (const float*)d_in[5];
  const float* b_k = (const float*)d_in[6];
  const float* w_v = (const float*)d_in[7];
  const float* b_v = (const float*)d_in[8];
  const float* w_o = (const float*)d_in[9];
  const float* b_o = (const float*)d_in[10];

  u16t* ws = (u16t*)d_ws;
  const size_t SZX = (size_t)S_LEN * DMODEL;   // 2^22
  const size_t SZW = (size_t)DMODEL * DMODEL;  // 2^20
  u16t* xq  = ws;
  u16t* xk  = xq + SZX;
  u16t* xv  = xk + SZX;
  u16t* wb0 = xv + SZX;
  u16t* wb1 = wb0 + SZW;
  u16t* wb2 = wb1 + SZW;
  u16t* wb3 = wb2 + SZW;
  u16t* Qp  = wb3 + SZW;
  u16t* Kp  = Qp + SZX;
  u16t* Vt  = Kp + SZX;   // V^T: [NHEADS*DKH][S_LEN]
  u16t* AO  = xk;         // dead after gemm_qkv
  float* pacc = (float*)xq;
  float* pml  = pacc + (size_t)NHEADS * NSPLIT * 64 * 64;

  dim3 blk(256);

  cvt_all<<<(int)((4 * SZW + 3 * SZX) / 1024), blk, 0, stream>>>(
      w_q, w_k, w_v, w_o, q, k, v, wb0, wb1, wb2, wb3, xq, xk, xv);

  gemm_qkv<<<768, blk, 0, stream>>>(xq, xk, xv, wb0, wb1, wb2, b_q, b_k, b_v, Qp, Kp, Vt);

  attn_kernel<<<dim3(63 + NSPLIT, NHEADS), blk, 0, stream>>>(Qp, Kp, Vt, AO, pacc, pml);
  merge_kernel<<<NHEADS, blk, 0, stream>>>(pacc, pml, AO);

  gemm_o<<<512, blk, 0, stream>>>(AO, wb3, b_o, (float*)d_out);
}

// Round 10
// 114.346 us; speedup vs baseline: 4.3369x; 1.0297x over previous
//
#include <hip/hip_runtime.h>

#define S_LEN 4096
#define DMODEL 1024
#define NHEADS 16
#define DKH 64
#define WIN 256
#define GTOK 64
#define NSPLIT 8

typedef unsigned short u16t;
typedef __attribute__((ext_vector_type(8))) short short8;
typedef __attribute__((ext_vector_type(4))) float f32x4;

__device__ __forceinline__ u16t f2bf(float x) {
  union { float f; unsigned int u; } v; v.f = x;
  unsigned int r = v.u + 0x7FFFu + ((v.u >> 16) & 1u);
  return (u16t)(r >> 16);
}

__device__ __forceinline__ unsigned int cvtpk(float lo, float hi) {
  unsigned int r;
  asm("v_cvt_pk_bf16_f32 %0, %1, %2" : "=v"(r) : "v"(lo), "v"(hi));
  return r;
}

__device__ __forceinline__ void gload_lds16(const u16t* g, u16t* l) {
  __builtin_amdgcn_global_load_lds(
      (const __attribute__((address_space(1))) void*)g,
      (__attribute__((address_space(3))) void*)l, 16, 0, 0);
}

// ---------------- fused fp32 -> bf16 convert (all 7 tensors, one launch) -------
__global__ void cvt_all(const float* __restrict__ s0, const float* __restrict__ s1,
                        const float* __restrict__ s2, const float* __restrict__ s3,
                        const float* __restrict__ s4, const float* __restrict__ s5,
                        const float* __restrict__ s6,
                        u16t* __restrict__ d0, u16t* __restrict__ d1,
                        u16t* __restrict__ d2, u16t* __restrict__ d3,
                        u16t* __restrict__ d4, u16t* __restrict__ d5,
                        u16t* __restrict__ d6) {
  size_t i = (size_t)blockIdx.x * 1024 + threadIdx.x * 4;
  const float* s; u16t* d; size_t local;
  if (i < ((size_t)4 << 20)) {          // 4 weight matrices, 2^20 each
    int which = (int)(i >> 20);
    local = i & ((1u << 20) - 1);
    s = which == 0 ? s0 : which == 1 ? s1 : which == 2 ? s2 : s3;
    d = which == 0 ? d0 : which == 1 ? d1 : which == 2 ? d2 : d3;
  } else {                              // 3 activations, 2^22 each
    size_t j = i - ((size_t)4 << 20);
    int which = (int)(j >> 22);
    local = j & ((1u << 22) - 1);
    s = which == 0 ? s4 : which == 1 ? s5 : s6;
    d = which == 0 ? d4 : which == 1 ? d5 : d6;
  }
  float4 f = *(const float4*)(s + local);
  unsigned int lo = (unsigned int)f2bf(f.x) | ((unsigned int)f2bf(f.y) << 16);
  unsigned int hi = (unsigned int)f2bf(f.z) | ((unsigned int)f2bf(f.w) << 16);
  *(uint2*)(d + local) = make_uint2(lo, hi);
}

// ---------------- bf16 GEMM body (m97 structure): Y = A @ B^T + bias, * alpha ----
#define BN 128
#define GBK 64

template<int OUT_F32, int BMT, int BIAS_ROW>
__device__ __forceinline__
void gemm_body(const u16t* __restrict__ A, const u16t* __restrict__ B,
               const float* __restrict__ bias, void* __restrict__ Y,
               int N, int K, float alpha, int m0, int n0)
{
  constexpr int MF = BMT / 32;
  constexpr int CA_ISS = BMT * 2 / 64;

  __shared__ __align__(16) u16t sA[BMT * GBK];
  __shared__ __align__(16) u16t sB[BN * GBK];

  const int tid = threadIdx.x;
  const int lane = tid & 63;
  const int lr = lane & 15, lg = lane >> 4;
  const int w = tid >> 6;
  const int wm = (w >> 1) * (MF * 16), wn = (w & 1) * 64;

  f32x4 acc[MF][4] = {};
  const int nk = K / GBK;

  for (int kt = 0; kt < nk; ++kt) {
    if (kt) __syncthreads();
#pragma unroll
    for (int i = 0; i < CA_ISS; ++i) {
      int c0 = w * (BMT * 2) + i * 64;
      int c = c0 + lane;
      int row = c >> 3, g = (c & 7) ^ (row & 7);
      gload_lds16(A + (size_t)(m0 + row) * K + kt * GBK + g * 8, sA + (size_t)c0 * 8);
    }
#pragma unroll
    for (int i = 0; i < 4; ++i) {
      int c0 = w * 256 + i * 64;
      int c = c0 + lane;
      int row = c >> 3, g = (c & 7) ^ (row & 7);
      gload_lds16(B + (size_t)(n0 + row) * K + kt * GBK + g * 8, sB + (size_t)c0 * 8);
    }
    __syncthreads();

    short8 af[MF][2], bf[4][2];
#pragma unroll
    for (int mf = 0; mf < MF; ++mf)
#pragma unroll
      for (int kk = 0; kk < 2; ++kk) {
        int s = ((kk * 4 + lg) ^ (lr & 7));
        af[mf][kk] = *(const short8*)&sA[(wm + mf * 16 + lr) * GBK + s * 8];
      }
#pragma unroll
    for (int nf = 0; nf < 4; ++nf)
#pragma unroll
      for (int kk = 0; kk < 2; ++kk) {
        int s = ((kk * 4 + lg) ^ (lr & 7));
        bf[nf][kk] = *(const short8*)&sB[(wn + nf * 16 + lr) * GBK + s * 8];
      }
    __builtin_amdgcn_s_setprio(1);
#pragma unroll
    for (int kk = 0; kk < 2; ++kk)
#pragma unroll
      for (int mf = 0; mf < MF; ++mf)
#pragma unroll
        for (int nf = 0; nf < 4; ++nf)
          acc[mf][nf] = __builtin_amdgcn_mfma_f32_16x16x32_bf16(af[mf][kk], bf[nf][kk], acc[mf][nf], 0, 0, 0);
    __builtin_amdgcn_s_setprio(0);
  }

#pragma unroll
  for (int nf = 0; nf < 4; ++nf) {
    int col = n0 + wn + nf * 16 + lr;
    float bvc = BIAS_ROW ? 0.f : bias[col];
#pragma unroll
    for (int mf = 0; mf < MF; ++mf)
#pragma unroll
      for (int r = 0; r < 4; ++r) {
        int row = m0 + wm + mf * 16 + lg * 4 + r;
        float bv = BIAS_ROW ? bias[row] : bvc;
        float v = (acc[mf][nf][r] + bv) * alpha;
        if (OUT_F32) ((float*)Y)[(size_t)row * N + col] = v;
        else         ((u16t*)Y)[(size_t)row * N + col] = f2bf(v);
      }
  }
}

// fused Q/K/V projection: 768 blocks (1D), bijective XCD swizzle (96 blocks/XCD)
// Q scaled by 1/sqrt(dk)*log2(e); V produced TRANSPOSED (V^T = Wv @ X^T).
#define QSCALE 0.18033688011112042f
__global__ __launch_bounds__(256)
void gemm_qkv(const u16t* __restrict__ xq, const u16t* __restrict__ xk, const u16t* __restrict__ xv,
              const u16t* __restrict__ wq, const u16t* __restrict__ wk, const u16t* __restrict__ wv,
              const float* __restrict__ bq, const float* __restrict__ bk, const float* __restrict__ bv,
              u16t* __restrict__ Qp, u16t* __restrict__ Kp, u16t* __restrict__ Vt)
{
  int b = blockIdx.x;
  int wid = (b & 7) * 96 + (b >> 3);
  int z = wid >> 8;
  int rem = wid & 255;
  if (z == 0) {
    gemm_body<0, 128, 0>(xq, wq, bq, Qp, DMODEL, DMODEL, QSCALE, (rem >> 3) * 128, (rem & 7) * BN);
  } else if (z == 1) {
    gemm_body<0, 128, 0>(xk, wk, bk, Kp, DMODEL, DMODEL, 1.0f, (rem >> 3) * 128, (rem & 7) * BN);
  } else {
    gemm_body<0, 128, 1>(wv, xv, bv, Vt, S_LEN, DMODEL, 1.0f, (rem & 7) * 128, (rem >> 3) * BN);
  }
}

__global__ __launch_bounds__(256)
void gemm_o(const u16t* __restrict__ A, const u16t* __restrict__ B,
            const float* __restrict__ bias, float* __restrict__ Y)
{
  int b = blockIdx.x;
  int wid = (b & 7) * 64 + (b >> 3);
  int my = wid >> 3, mx = wid & 7;
  gemm_body<1, 64, 0>(A, B, bias, Y, DMODEL, DMODEL, 1.0f, my * 64, mx * BN);
}

// ---------------- flash-style sparse attention (swapped QK^T, gload_lds dbuf) ----
// 1D grid 1136 = 8 XCDs x 142; each XCD gets 142 consecutive work ids = 2 heads
// -> K/V/Q for its heads fit per-XCD L2 (3 MB < 4 MB): staging loads become L2 hits.
__global__ __launch_bounds__(256)
void attn_kernel(const u16t* __restrict__ Qp, const u16t* __restrict__ Kp,
                 const u16t* __restrict__ Vt, u16t* __restrict__ AO,
                 float* __restrict__ pacc, float* __restrict__ pml)
{
  // 16 + 16 + 8 = 40 KB exactly -> 4 blocks/CU
  __shared__ __align__(16) u16t sK[2][64 * 64];
  __shared__ __align__(16) u16t sV[2][64 * 64];
  __shared__ __align__(16) u16t sP[4][16 * 64];

  const int b = blockIdx.x;                    // 0..1135
  const int wid = (b & 7) * 142 + (b >> 3);    // XCD-contiguous work id
  const int h = wid / 71;
  const int x = wid % 71;                      // 0..70 within head

  const int tid = threadIdx.x, w = tid >> 6, lane = tid & 63;
  const int lr = lane & 15, lg = lane >> 4;

  const bool windowed = (x < 63);
  const int qb = windowed ? (x + 1) : 0;
  const int split = windowed ? 0 : (x - 63);
  const int qw = qb * 64 + w * 16;

  short8 qf[2];
#pragma unroll
  for (int kk = 0; kk < 2; ++kk)
    qf[kk] = *(const short8*)(Qp + (size_t)(qw + lr) * DMODEL + h * DKH + kk * 32 + lg * 8);

  f32x4 acc[4] = {};
  float m_run = -1e30f, l_run = 0.f;  // per-lane: this lane's q row is qw+lr

  int lo = 1, nkv;
  if (windowed) {
    lo = (qb - 4 < 1) ? 1 : qb - 4;
    int hi = (qb + 4 > 63) ? 63 : qb + 4;
    nkv = hi - lo + 2;  // {0} ∪ [lo..hi]
  } else {
    nkv = 64 / NSPLIT;
  }

#define KVB(idx) (windowed ? ((idx) == 0 ? 0 : lo + (idx) - 1) : (split * (64 / NSPLIT) + (idx)))

  auto stage = [&](int buf, int kvb) {
    int kv0 = kvb * 64;
#pragma unroll
    for (int j = 0; j < 2; ++j) {
      int c = tid + j * 256;
      int row = c >> 3, g = (c & 7) ^ (row & 7);
      gload_lds16(Kp + (size_t)(kv0 + row) * DMODEL + h * DKH + g * 8, &sK[buf][c * 8]);
    }
#pragma unroll
    for (int j = 0; j < 2; ++j) {
      int c = tid + j * 256;
      int row = c >> 3, g = (c & 7) ^ (row & 7);
      gload_lds16(Vt + (size_t)(h * DKH + row) * S_LEN + kv0 + g * 8, &sV[buf][c * 8]);
    }
  };

  stage(0, KVB(0));
  __syncthreads();

  for (int idx = 0; idx < nkv; ++idx) {
    const int buf = idx & 1;
    const int kvb = KVB(idx);
    const int kv0 = kvb * 64;

    if (idx + 1 < nkv) stage(buf ^ 1, KVB(idx + 1));

    // S^T = K Q^T: sacc[nf][r] = S[k = kv0 + nf*16 + lg*4 + r][q = qw + lr]
    f32x4 sacc[4] = {};
    __builtin_amdgcn_s_setprio(1);
#pragma unroll
    for (int kk = 0; kk < 2; ++kk)
#pragma unroll
      for (int nf = 0; nf < 4; ++nf) {
        int s = ((kk * 4 + lg) ^ (lr & 7));
        short8 kf = *(const short8*)&sK[buf][(nf * 16 + lr) * 64 + s * 8];
        sacc[nf] = __builtin_amdgcn_mfma_f32_16x16x32_bf16(kf, qf[kk], sacc[nf], 0, 0, 0);
      }
    __builtin_amdgcn_s_setprio(0);

    // mask: only the two edge tiles can mask, and NEVER the global tile kvb==0
    if (windowed && (kvb == qb + 4 || (kvb == qb - 4 && kvb > 0))) {
      int qg = qw + lr;
#pragma unroll
      for (int nf = 0; nf < 4; ++nf)
#pragma unroll
        for (int r = 0; r < 4; ++r) {
          int sg = kv0 + nf * 16 + lg * 4 + r;
          int diff = qg - sg; if (diff < 0) diff = -diff;
          if (diff > WIN) sacc[nf][r] = -1e30f;
        }
    }

    // online softmax, exp2 domain; lane owns q = qw+lr (reduce over lg groups)
    float rm0 = fmaxf(fmaxf(sacc[0][0], sacc[0][1]), sacc[0][2]);
    float rm1 = fmaxf(fmaxf(sacc[0][3], sacc[1][0]), sacc[1][1]);
    float rm2 = fmaxf(fmaxf(sacc[1][2], sacc[1][3]), sacc[2][0]);
    float rm3 = fmaxf(fmaxf(sacc[2][1], sacc[2][2]), sacc[2][3]);
    float rm4 = fmaxf(fmaxf(sacc[3][0], sacc[3][1]), sacc[3][2]);
    float rm = fmaxf(fmaxf(rm0, rm1), fmaxf(fmaxf(rm2, rm3), fmaxf(rm4, sacc[3][3])));
    rm = fmaxf(rm, __shfl_xor(rm, 16));
    rm = fmaxf(rm, __shfl_xor(rm, 32));

    // defer-max (T13): skip rescale unless max jumped by > 11 bits (~8 nats)
    if (!__all(rm <= m_run + 11.0f)) {
      float mnew = fmaxf(m_run, rm);
      float corr = exp2f(m_run - mnew);
      m_run = mnew;
      l_run *= corr;
      float cq[4];
#pragma unroll
      for (int r = 0; r < 4; ++r) cq[r] = __shfl(corr, lg * 4 + r);
#pragma unroll
      for (int nf = 0; nf < 4; ++nf)
#pragma unroll
        for (int r = 0; r < 4; ++r) acc[nf][r] *= cq[r];
    }

    float p[4][4];
    float rs = 0.f;
#pragma unroll
    for (int nf = 0; nf < 4; ++nf)
#pragma unroll
      for (int r = 0; r < 4; ++r) {
        float e = exp2f(sacc[nf][r] - m_run);
        p[nf][r] = e;
        rs += e;
      }
    rs += __shfl_xor(rs, 16);
    rs += __shfl_xor(rs, 32);
    l_run += rs;

    // P -> LDS via v_cvt_pk_bf16_f32; stride 64 with XOR-block swizzle
#pragma unroll
    for (int nf = 0; nf < 4; ++nf) {
      unsigned int lo32 = cvtpk(p[nf][0], p[nf][1]);
      unsigned int hi32 = cvtpk(p[nf][2], p[nf][3]);
      int blk = (nf * 2 + (lg >> 1)) ^ (lr & 7);
      *(uint2*)&sP[w][lr * 64 + blk * 8 + (lg & 1) * 4] = make_uint2(lo32, hi32);
    }

    // O += P V : pf reads block kk*4+lg (same XOR); vf = V^T row d = nf*16+lr
#pragma unroll
    for (int kk = 0; kk < 2; ++kk) {
      short8 pf = *(const short8*)&sP[w][lr * 64 + (((kk * 4 + lg) ^ (lr & 7))) * 8];
      __builtin_amdgcn_s_setprio(1);
#pragma unroll
      for (int nf = 0; nf < 4; ++nf) {
        int s = ((kk * 4 + lg) ^ (lr & 7));
        short8 vf = *(const short8*)&sV[buf][(nf * 16 + lr) * 64 + s * 8];
        acc[nf] = __builtin_amdgcn_mfma_f32_16x16x32_bf16(pf, vf, acc[nf], 0, 0, 0);
      }
      __builtin_amdgcn_s_setprio(0);
    }

    if (idx + 1 < nkv) __syncthreads();  // drains next-tile gloads + joins waves
  }
#undef KVB

  if (windowed) {
    float lq[4];
#pragma unroll
    for (int r = 0; r < 4; ++r) lq[r] = __shfl(l_run, lg * 4 + r);
#pragma unroll
    for (int nf = 0; nf < 4; ++nf)
#pragma unroll
      for (int r = 0; r < 4; ++r) {
        float v = acc[nf][r] / lq[r];
        AO[(size_t)(qw + lg * 4 + r) * DMODEL + h * DKH + nf * 16 + lr] = f2bf(v);
      }
  } else {
    const int pbase = (h * NSPLIT + split) * 64;
#pragma unroll
    for (int nf = 0; nf < 4; ++nf)
#pragma unroll
      for (int r = 0; r < 4; ++r)
        pacc[(size_t)(pbase + w * 16 + lg * 4 + r) * 64 + nf * 16 + lr] = acc[nf][r];
    if (lane < 16) {
      int bb = (pbase + w * 16 + lane) * 2;
      pml[bb] = m_run;
      pml[bb + 1] = l_run;
    }
  }
}

// ---------------- merge partials for global q rows (exp2 domain) ----------------
__global__ __launch_bounds__(256)
void merge_kernel(const float* __restrict__ pacc, const float* __restrict__ pml,
                  u16t* __restrict__ AO)
{
  const int h = blockIdx.x;
  const int tid = threadIdx.x;
  const int row = tid >> 2;
  const int d0 = (tid & 3) * 16;

  float M = -1e30f;
#pragma unroll
  for (int s = 0; s < NSPLIT; ++s)
    M = fmaxf(M, pml[((h * NSPLIT + s) * 64 + row) * 2]);

  float L = 0.f;
  float o[16];
#pragma unroll
  for (int e = 0; e < 16; ++e) o[e] = 0.f;

#pragma unroll
  for (int s = 0; s < NSPLIT; ++s) {
    int b = ((h * NSPLIT + s) * 64 + row) * 2;
    float sc = exp2f(pml[b] - M);
    L += pml[b + 1] * sc;
    const float4* a = (const float4*)(pacc + ((size_t)(h * NSPLIT + s) * 64 + row) * 64 + d0);
#pragma unroll
    for (int q4 = 0; q4 < 4; ++q4) {
      float4 av = a[q4];
      o[q4 * 4 + 0] += av.x * sc;
      o[q4 * 4 + 1] += av.y * sc;
      o[q4 * 4 + 2] += av.z * sc;
      o[q4 * 4 + 3] += av.w * sc;
    }
  }
  float inv = 1.f / L;
#pragma unroll
  for (int e = 0; e < 16; ++e)
    AO[(size_t)row * DMODEL + h * DKH + d0 + e] = f2bf(o[e] * inv);
}

// ---------------- launch ----------------
extern "C" void kernel_launch(void* const* d_in, const int* in_sizes, int n_in,
                              void* d_out, int out_size, void* d_ws, size_t ws_size,
                              hipStream_t stream) {
  const float* q   = (const float*)d_in[0];
  const float* k   = (const float*)d_in[1];
  const float* v   = (const float*)d_in[2];
  const float* w_q = (const float*)d_in[3];
  const float* b_q = (const float*)d_in[4];
  const float* w_k = (const float*)d_in[5];
  const float* b_k = (const float*)d_in[6];
  const float* w_v = (const float*)d_in[7];
  const float* b_v = (const float*)d_in[8];
  const float* w_o = (const float*)d_in[9];
  const float* b_o = (const float*)d_in[10];

  u16t* ws = (u16t*)d_ws;
  const size_t SZX = (size_t)S_LEN * DMODEL;   // 2^22
  const size_t SZW = (size_t)DMODEL * DMODEL;  // 2^20
  u16t* xq  = ws;
  u16t* xk  = xq + SZX;
  u16t* xv  = xk + SZX;
  u16t* wb0 = xv + SZX;
  u16t* wb1 = wb0 + SZW;
  u16t* wb2 = wb1 + SZW;
  u16t* wb3 = wb2 + SZW;
  u16t* Qp  = wb3 + SZW;
  u16t* Kp  = Qp + SZX;
  u16t* Vt  = Kp + SZX;   // V^T: [NHEADS*DKH][S_LEN]
  u16t* AO  = xk;         // dead after gemm_qkv
  float* pacc = (float*)xq;
  float* pml  = pacc + (size_t)NHEADS * NSPLIT * 64 * 64;

  dim3 blk(256);

  cvt_all<<<(int)((4 * SZW + 3 * SZX) / 1024), blk, 0, stream>>>(
      w_q, w_k, w_v, w_o, q, k, v, wb0, wb1, wb2, wb3, xq, xk, xv);

  gemm_qkv<<<768, blk, 0, stream>>>(xq, xk, xv, wb0, wb1, wb2, b_q, b_k, b_v, Qp, Kp, Vt);

  attn_kernel<<<(63 + NSPLIT) * NHEADS, blk, 0, stream>>>(Qp, Kp, Vt, AO, pacc, pml);
  merge_kernel<<<NHEADS, blk, 0, stream>>>(pacc, pml, AO);

  gemm_o<<<512, blk, 0, stream>>>(AO, wb3, b_o, (float*)d_out);
}

// Round 11
// 113.143 us; speedup vs baseline: 4.3830x; 1.0106x over previous
//
#include <hip/hip_runtime.h>

#define S_LEN 4096
#define DMODEL 1024
#define NHEADS 16
#define DKH 64
#define WIN 256
#define GTOK 64
#define NSPLIT 8

typedef unsigned short u16t;
typedef __attribute__((ext_vector_type(8))) short short8;
typedef __attribute__((ext_vector_type(4))) float f32x4;

__device__ __forceinline__ u16t f2bf(float x) {
  union { float f; unsigned int u; } v; v.f = x;
  unsigned int r = v.u + 0x7FFFu + ((v.u >> 16) & 1u);
  return (u16t)(r >> 16);
}

__device__ __forceinline__ unsigned int cvtpk(float lo, float hi) {
  unsigned int r;
  asm("v_cvt_pk_bf16_f32 %0, %1, %2" : "=v"(r) : "v"(lo), "v"(hi));
  return r;
}

__device__ __forceinline__ void gload_lds16(const u16t* g, u16t* l) {
  __builtin_amdgcn_global_load_lds(
      (const __attribute__((address_space(1))) void*)g,
      (__attribute__((address_space(3))) void*)l, 16, 0, 0);
}

// ---------------- fused fp32 -> bf16 convert (all 7 tensors, one launch) -------
__global__ void cvt_all(const float* __restrict__ s0, const float* __restrict__ s1,
                        const float* __restrict__ s2, const float* __restrict__ s3,
                        const float* __restrict__ s4, const float* __restrict__ s5,
                        const float* __restrict__ s6,
                        u16t* __restrict__ d0, u16t* __restrict__ d1,
                        u16t* __restrict__ d2, u16t* __restrict__ d3,
                        u16t* __restrict__ d4, u16t* __restrict__ d5,
                        u16t* __restrict__ d6) {
  size_t i = (size_t)blockIdx.x * 1024 + threadIdx.x * 4;
  const float* s; u16t* d; size_t local;
  if (i < ((size_t)4 << 20)) {          // 4 weight matrices, 2^20 each
    int which = (int)(i >> 20);
    local = i & ((1u << 20) - 1);
    s = which == 0 ? s0 : which == 1 ? s1 : which == 2 ? s2 : s3;
    d = which == 0 ? d0 : which == 1 ? d1 : which == 2 ? d2 : d3;
  } else {                              // 3 activations, 2^22 each
    size_t j = i - ((size_t)4 << 20);
    int which = (int)(j >> 22);
    local = j & ((1u << 22) - 1);
    s = which == 0 ? s4 : which == 1 ? s5 : s6;
    d = which == 0 ? d4 : which == 1 ? d5 : d6;
  }
  float4 f = *(const float4*)(s + local);
  unsigned int lo = (unsigned int)f2bf(f.x) | ((unsigned int)f2bf(f.y) << 16);
  unsigned int hi = (unsigned int)f2bf(f.z) | ((unsigned int)f2bf(f.w) << 16);
  *(uint2*)(d + local) = make_uint2(lo, hi);
}

// ---------------- bf16 GEMM body (m97 structure): Y = A @ B^T + bias, * alpha ----
// Shared memory is provided by the caller so multiple template instantiations in
// one kernel share ONE allocation (in-body __shared__ duplicated: 64KB, 2 blk/CU).
#define BN 128
#define GBK 64

template<int OUT_F32, int BMT, int BIAS_ROW>
__device__ __forceinline__
void gemm_body(u16t* __restrict__ sA, u16t* __restrict__ sB,
               const u16t* __restrict__ A, const u16t* __restrict__ B,
               const float* __restrict__ bias, void* __restrict__ Y,
               int N, int K, float alpha, int m0, int n0)
{
  constexpr int MF = BMT / 32;
  constexpr int CA_ISS = BMT * 2 / 64;

  const int tid = threadIdx.x;
  const int lane = tid & 63;
  const int lr = lane & 15, lg = lane >> 4;
  const int w = tid >> 6;
  const int wm = (w >> 1) * (MF * 16), wn = (w & 1) * 64;

  f32x4 acc[MF][4] = {};
  const int nk = K / GBK;

  for (int kt = 0; kt < nk; ++kt) {
    if (kt) __syncthreads();
#pragma unroll
    for (int i = 0; i < CA_ISS; ++i) {
      int c0 = w * (BMT * 2) + i * 64;
      int c = c0 + lane;
      int row = c >> 3, g = (c & 7) ^ (row & 7);
      gload_lds16(A + (size_t)(m0 + row) * K + kt * GBK + g * 8, sA + (size_t)c0 * 8);
    }
#pragma unroll
    for (int i = 0; i < 4; ++i) {
      int c0 = w * 256 + i * 64;
      int c = c0 + lane;
      int row = c >> 3, g = (c & 7) ^ (row & 7);
      gload_lds16(B + (size_t)(n0 + row) * K + kt * GBK + g * 8, sB + (size_t)c0 * 8);
    }
    __syncthreads();

    short8 af[MF][2], bf[4][2];
#pragma unroll
    for (int mf = 0; mf < MF; ++mf)
#pragma unroll
      for (int kk = 0; kk < 2; ++kk) {
        int s = ((kk * 4 + lg) ^ (lr & 7));
        af[mf][kk] = *(const short8*)&sA[(wm + mf * 16 + lr) * GBK + s * 8];
      }
#pragma unroll
    for (int nf = 0; nf < 4; ++nf)
#pragma unroll
      for (int kk = 0; kk < 2; ++kk) {
        int s = ((kk * 4 + lg) ^ (lr & 7));
        bf[nf][kk] = *(const short8*)&sB[(wn + nf * 16 + lr) * GBK + s * 8];
      }
    __builtin_amdgcn_s_setprio(1);
#pragma unroll
    for (int kk = 0; kk < 2; ++kk)
#pragma unroll
      for (int mf = 0; mf < MF; ++mf)
#pragma unroll
        for (int nf = 0; nf < 4; ++nf)
          acc[mf][nf] = __builtin_amdgcn_mfma_f32_16x16x32_bf16(af[mf][kk], bf[nf][kk], acc[mf][nf], 0, 0, 0);
    __builtin_amdgcn_s_setprio(0);
  }

#pragma unroll
  for (int nf = 0; nf < 4; ++nf) {
    int col = n0 + wn + nf * 16 + lr;
    float bvc = BIAS_ROW ? 0.f : bias[col];
#pragma unroll
    for (int mf = 0; mf < MF; ++mf)
#pragma unroll
      for (int r = 0; r < 4; ++r) {
        int row = m0 + wm + mf * 16 + lg * 4 + r;
        float bv = BIAS_ROW ? bias[row] : bvc;
        float v = (acc[mf][nf][r] + bv) * alpha;
        if (OUT_F32) ((float*)Y)[(size_t)row * N + col] = v;
        else         ((u16t*)Y)[(size_t)row * N + col] = f2bf(v);
      }
  }
}

// fused Q/K/V projection: 768 blocks (1D), bijective XCD swizzle (96 blocks/XCD)
// Q scaled by 1/sqrt(dk)*log2(e); V produced TRANSPOSED (V^T = Wv @ X^T).
// One 32 KB shared allocation for all branches -> 3+ blocks/CU co-resident.
#define QSCALE 0.18033688011112042f
__global__ __launch_bounds__(256)
void gemm_qkv(const u16t* __restrict__ xq, const u16t* __restrict__ xk, const u16t* __restrict__ xv,
              const u16t* __restrict__ wq, const u16t* __restrict__ wk, const u16t* __restrict__ wv,
              const float* __restrict__ bq, const float* __restrict__ bk, const float* __restrict__ bv,
              u16t* __restrict__ Qp, u16t* __restrict__ Kp, u16t* __restrict__ Vt)
{
  __shared__ __align__(16) u16t smem[2 * 128 * GBK];  // 32 KB total
  u16t* sA = smem;
  u16t* sB = smem + 128 * GBK;

  int b = blockIdx.x;
  int wid = (b & 7) * 96 + (b >> 3);
  int z = wid >> 8;
  int rem = wid & 255;
  if (z == 0) {
    gemm_body<0, 128, 0>(sA, sB, xq, wq, bq, Qp, DMODEL, DMODEL, QSCALE, (rem >> 3) * 128, (rem & 7) * BN);
  } else if (z == 1) {
    gemm_body<0, 128, 0>(sA, sB, xk, wk, bk, Kp, DMODEL, DMODEL, 1.0f, (rem >> 3) * 128, (rem & 7) * BN);
  } else {
    gemm_body<0, 128, 1>(sA, sB, wv, xv, bv, Vt, S_LEN, DMODEL, 1.0f, (rem & 7) * 128, (rem >> 3) * BN);
  }
}

__global__ __launch_bounds__(256)
void gemm_o(const u16t* __restrict__ A, const u16t* __restrict__ B,
            const float* __restrict__ bias, float* __restrict__ Y)
{
  __shared__ __align__(16) u16t smem[(64 + 128) * GBK];  // 24 KB
  u16t* sA = smem;
  u16t* sB = smem + 64 * GBK;

  int b = blockIdx.x;
  int wid = (b & 7) * 64 + (b >> 3);
  int my = wid >> 3, mx = wid & 7;
  gemm_body<1, 64, 0>(sA, sB, A, B, bias, Y, DMODEL, DMODEL, 1.0f, my * 64, mx * BN);
}

// ---------------- flash-style sparse attention (swapped QK^T, gload_lds dbuf) ----
// 1D grid 1136 = 8 XCDs x 142; each XCD gets 142 consecutive work ids = 2 heads
// -> K/V/Q for its heads fit per-XCD L2 (3 MB < 4 MB): staging loads become L2 hits.
__global__ __launch_bounds__(256)
void attn_kernel(const u16t* __restrict__ Qp, const u16t* __restrict__ Kp,
                 const u16t* __restrict__ Vt, u16t* __restrict__ AO,
                 float* __restrict__ pacc, float* __restrict__ pml)
{
  // 16 + 16 + 8 = 40 KB exactly -> 4 blocks/CU
  __shared__ __align__(16) u16t sK[2][64 * 64];
  __shared__ __align__(16) u16t sV[2][64 * 64];
  __shared__ __align__(16) u16t sP[4][16 * 64];

  const int b = blockIdx.x;                    // 0..1135
  const int wid = (b & 7) * 142 + (b >> 3);    // XCD-contiguous work id
  const int h = wid / 71;
  const int x = wid % 71;                      // 0..70 within head

  const int tid = threadIdx.x, w = tid >> 6, lane = tid & 63;
  const int lr = lane & 15, lg = lane >> 4;

  const bool windowed = (x < 63);
  const int qb = windowed ? (x + 1) : 0;
  const int split = windowed ? 0 : (x - 63);
  const int qw = qb * 64 + w * 16;

  short8 qf[2];
#pragma unroll
  for (int kk = 0; kk < 2; ++kk)
    qf[kk] = *(const short8*)(Qp + (size_t)(qw + lr) * DMODEL + h * DKH + kk * 32 + lg * 8);

  f32x4 acc[4] = {};
  float m_run = -1e30f, l_run = 0.f;  // per-lane: this lane's q row is qw+lr

  int lo = 1, nkv;
  if (windowed) {
    lo = (qb - 4 < 1) ? 1 : qb - 4;
    int hi = (qb + 4 > 63) ? 63 : qb + 4;
    nkv = hi - lo + 2;  // {0} ∪ [lo..hi]
  } else {
    nkv = 64 / NSPLIT;
  }

#define KVB(idx) (windowed ? ((idx) == 0 ? 0 : lo + (idx) - 1) : (split * (64 / NSPLIT) + (idx)))

  auto stage = [&](int buf, int kvb) {
    int kv0 = kvb * 64;
#pragma unroll
    for (int j = 0; j < 2; ++j) {
      int c = tid + j * 256;
      int row = c >> 3, g = (c & 7) ^ (row & 7);
      gload_lds16(Kp + (size_t)(kv0 + row) * DMODEL + h * DKH + g * 8, &sK[buf][c * 8]);
    }
#pragma unroll
    for (int j = 0; j < 2; ++j) {
      int c = tid + j * 256;
      int row = c >> 3, g = (c & 7) ^ (row & 7);
      gload_lds16(Vt + (size_t)(h * DKH + row) * S_LEN + kv0 + g * 8, &sV[buf][c * 8]);
    }
  };

  stage(0, KVB(0));
  __syncthreads();

  for (int idx = 0; idx < nkv; ++idx) {
    const int buf = idx & 1;
    const int kvb = KVB(idx);
    const int kv0 = kvb * 64;

    if (idx + 1 < nkv) stage(buf ^ 1, KVB(idx + 1));

    // S^T = K Q^T: sacc[nf][r] = S[k = kv0 + nf*16 + lg*4 + r][q = qw + lr]
    f32x4 sacc[4] = {};
    __builtin_amdgcn_s_setprio(1);
#pragma unroll
    for (int kk = 0; kk < 2; ++kk)
#pragma unroll
      for (int nf = 0; nf < 4; ++nf) {
        int s = ((kk * 4 + lg) ^ (lr & 7));
        short8 kf = *(const short8*)&sK[buf][(nf * 16 + lr) * 64 + s * 8];
        sacc[nf] = __builtin_amdgcn_mfma_f32_16x16x32_bf16(kf, qf[kk], sacc[nf], 0, 0, 0);
      }
    __builtin_amdgcn_s_setprio(0);

    // mask: only the two edge tiles can mask, and NEVER the global tile kvb==0
    if (windowed && (kvb == qb + 4 || (kvb == qb - 4 && kvb > 0))) {
      int qg = qw + lr;
#pragma unroll
      for (int nf = 0; nf < 4; ++nf)
#pragma unroll
        for (int r = 0; r < 4; ++r) {
          int sg = kv0 + nf * 16 + lg * 4 + r;
          int diff = qg - sg; if (diff < 0) diff = -diff;
          if (diff > WIN) sacc[nf][r] = -1e30f;
        }
    }

    // online softmax, exp2 domain; lane owns q = qw+lr (reduce over lg groups)
    float rm0 = fmaxf(fmaxf(sacc[0][0], sacc[0][1]), sacc[0][2]);
    float rm1 = fmaxf(fmaxf(sacc[0][3], sacc[1][0]), sacc[1][1]);
    float rm2 = fmaxf(fmaxf(sacc[1][2], sacc[1][3]), sacc[2][0]);
    float rm3 = fmaxf(fmaxf(sacc[2][1], sacc[2][2]), sacc[2][3]);
    float rm4 = fmaxf(fmaxf(sacc[3][0], sacc[3][1]), sacc[3][2]);
    float rm = fmaxf(fmaxf(rm0, rm1), fmaxf(fmaxf(rm2, rm3), fmaxf(rm4, sacc[3][3])));
    rm = fmaxf(rm, __shfl_xor(rm, 16));
    rm = fmaxf(rm, __shfl_xor(rm, 32));

    // defer-max (T13): skip rescale unless max jumped by > 11 bits (~8 nats)
    if (!__all(rm <= m_run + 11.0f)) {
      float mnew = fmaxf(m_run, rm);
      float corr = exp2f(m_run - mnew);
      m_run = mnew;
      l_run *= corr;
      float cq[4];
#pragma unroll
      for (int r = 0; r < 4; ++r) cq[r] = __shfl(corr, lg * 4 + r);
#pragma unroll
      for (int nf = 0; nf < 4; ++nf)
#pragma unroll
        for (int r = 0; r < 4; ++r) acc[nf][r] *= cq[r];
    }

    float p[4][4];
    float rs = 0.f;
#pragma unroll
    for (int nf = 0; nf < 4; ++nf)
#pragma unroll
      for (int r = 0; r < 4; ++r) {
        float e = exp2f(sacc[nf][r] - m_run);
        p[nf][r] = e;
        rs += e;
      }
    rs += __shfl_xor(rs, 16);
    rs += __shfl_xor(rs, 32);
    l_run += rs;

    // P -> LDS via v_cvt_pk_bf16_f32; stride 64 with XOR-block swizzle
#pragma unroll
    for (int nf = 0; nf < 4; ++nf) {
      unsigned int lo32 = cvtpk(p[nf][0], p[nf][1]);
      unsigned int hi32 = cvtpk(p[nf][2], p[nf][3]);
      int blk = (nf * 2 + (lg >> 1)) ^ (lr & 7);
      *(uint2*)&sP[w][lr * 64 + blk * 8 + (lg & 1) * 4] = make_uint2(lo32, hi32);
    }

    // O += P V : pf reads block kk*4+lg (same XOR); vf = V^T row d = nf*16+lr
#pragma unroll
    for (int kk = 0; kk < 2; ++kk) {
      short8 pf = *(const short8*)&sP[w][lr * 64 + (((kk * 4 + lg) ^ (lr & 7))) * 8];
      __builtin_amdgcn_s_setprio(1);
#pragma unroll
      for (int nf = 0; nf < 4; ++nf) {
        int s = ((kk * 4 + lg) ^ (lr & 7));
        short8 vf = *(const short8*)&sV[buf][(nf * 16 + lr) * 64 + s * 8];
        acc[nf] = __builtin_amdgcn_mfma_f32_16x16x32_bf16(pf, vf, acc[nf], 0, 0, 0);
      }
      __builtin_amdgcn_s_setprio(0);
    }

    if (idx + 1 < nkv) __syncthreads();  // drains next-tile gloads + joins waves
  }
#undef KVB

  if (windowed) {
    float lq[4];
#pragma unroll
    for (int r = 0; r < 4; ++r) lq[r] = __shfl(l_run, lg * 4 + r);
#pragma unroll
    for (int nf = 0; nf < 4; ++nf)
#pragma unroll
      for (int r = 0; r < 4; ++r) {
        float v = acc[nf][r] / lq[r];
        AO[(size_t)(qw + lg * 4 + r) * DMODEL + h * DKH + nf * 16 + lr] = f2bf(v);
      }
  } else {
    const int pbase = (h * NSPLIT + split) * 64;
#pragma unroll
    for (int nf = 0; nf < 4; ++nf)
#pragma unroll
      for (int r = 0; r < 4; ++r)
        pacc[(size_t)(pbase + w * 16 + lg * 4 + r) * 64 + nf * 16 + lr] = acc[nf][r];
    if (lane < 16) {
      int bb = (pbase + w * 16 + lane) * 2;
      pml[bb] = m_run;
      pml[bb + 1] = l_run;
    }
  }
}

// ---------------- merge partials for global q rows (exp2 domain) ----------------
__global__ __launch_bounds__(256)
void merge_kernel(const float* __restrict__ pacc, const float* __restrict__ pml,
                  u16t* __restrict__ AO)
{
  const int h = blockIdx.x;
  const int tid = threadIdx.x;
  const int row = tid >> 2;
  const int d0 = (tid & 3) * 16;

  float M = -1e30f;
#pragma unroll
  for (int s = 0; s < NSPLIT; ++s)
    M = fmaxf(M, pml[((h * NSPLIT + s) * 64 + row) * 2]);

  float L = 0.f;
  float o[16];
#pragma unroll
  for (int e = 0; e < 16; ++e) o[e] = 0.f;

#pragma unroll
  for (int s = 0; s < NSPLIT; ++s) {
    int b = ((h * NSPLIT + s) * 64 + row) * 2;
    float sc = exp2f(pml[b] - M);
    L += pml[b + 1] * sc;
    const float4* a = (const float4*)(pacc + ((size_t)(h * NSPLIT + s) * 64 + row) * 64 + d0);
#pragma unroll
    for (int q4 = 0; q4 < 4; ++q4) {
      float4 av = a[q4];
      o[q4 * 4 + 0] += av.x * sc;
      o[q4 * 4 + 1] += av.y * sc;
      o[q4 * 4 + 2] += av.z * sc;
      o[q4 * 4 + 3] += av.w * sc;
    }
  }
  float inv = 1.f / L;
#pragma unroll
  for (int e = 0; e < 16; ++e)
    AO[(size_t)row * DMODEL + h * DKH + d0 + e] = f2bf(o[e] * inv);
}

// ---------------- launch ----------------
extern "C" void kernel_launch(void* const* d_in, const int* in_sizes, int n_in,
                              void* d_out, int out_size, void* d_ws, size_t ws_size,
                              hipStream_t stream) {
  const float* q   = (const float*)d_in[0];
  const float* k   = (const float*)d_in[1];
  const float* v   = (const float*)d_in[2];
  const float* w_q = (const float*)d_in[3];
  const float* b_q = (const float*)d_in[4];
  const float* w_k = (const float*)d_in[5];
  const float* b_k = (const float*)d_in[6];
  const float* w_v = (const float*)d_in[7];
  const float* b_v = (const float*)d_in[8];
  const float* w_o = (const float*)d_in[9];
  const float* b_o = (const float*)d_in[10];

  u16t* ws = (u16t*)d_ws;
  const size_t SZX = (size_t)S_LEN * DMODEL;   // 2^22
  const size_t SZW = (size_t)DMODEL * DMODEL;  // 2^20
  u16t* xq  = ws;
  u16t* xk  = xq + SZX;
  u16t* xv  = xk + SZX;
  u16t* wb0 = xv + SZX;
  u16t* wb1 = wb0 + SZW;
  u16t* wb2 = wb1 + SZW;
  u16t* wb3 = wb2 + SZW;
  u16t* Qp  = wb3 + SZW;
  u16t* Kp  = Qp + SZX;
  u16t* Vt  = Kp + SZX;   // V^T: [NHEADS*DKH][S_LEN]
  u16t* AO  = xk;         // dead after gemm_qkv
  float* pacc = (float*)xq;
  float* pml  = pacc + (size_t)NHEADS * NSPLIT * 64 * 64;

  dim3 blk(256);

  cvt_all<<<(int)((4 * SZW + 3 * SZX) / 1024), blk, 0, stream>>>(
      w_q, w_k, w_v, w_o, q, k, v, wb0, wb1, wb2, wb3, xq, xk, xv);

  gemm_qkv<<<768, blk, 0, stream>>>(xq, xk, xv, wb0, wb1, wb2, b_q, b_k, b_v, Qp, Kp, Vt);

  attn_kernel<<<(63 + NSPLIT) * NHEADS, blk, 0, stream>>>(Qp, Kp, Vt, AO, pacc, pml);
  merge_kernel<<<NHEADS, blk, 0, stream>>>(pacc, pml, AO);

  gemm_o<<<512, blk, 0, stream>>>(AO, wb3, b_o, (float*)d_out);
}